// Round 3
// baseline (8454.678 us; speedup 1.0000x reference)
//
#include <hip/hip_runtime.h>
#include <stdint.h>

// ---------------------------------------------------------------------------
// TreeLSTMParser: N=2048 nodes/timesteps, D_IN=H=768, OUT=128.
// Tree: complete binary tree, parent(i)=(i-1)/2; level L = [2^(10-L),2^(11-L))
// for L=1..10, level 0 = leaves [1024,2048), level 11 = {0}.
//
// Inputs fp32 (detector-confirmed r3).  All tensors canonicalized to bf16.
//
// seq_lstm v7: 48 wgs x 1024 threads, PACKED uint4 weights (spill-proof).
// r8 post-mortem of v6: VGPR_Count=48 < 48 weight regs + working set =>
// compiler re-materialized fp32 weights from global EVERY step (FETCH 176MB).
// fp32-weight promotion has now failed twice (v5 wf[96], v6 named f32x4);
// only v4's packed-uint4-array idiom is proven resident (VGPR=64).
// r8 model: LDS reads are 4-lane BROADCAST (gate lanes share addresses) =>
// LDS phase was never dominant; VALUBusy 5.4% chip-wide = ~57% on the 24
// active CUs = ~3000cyc/step of VALU issue.  Cut MACs/thread 96->48 by
// spreading to 48 WGs (16 j each, 16 K-parts x 48 cols), weights 6 uint4
// = 24 VGPRs.  Single barrier via parity LDS (v5/v6-proven).  Poll protocol
// identical to v4: tag-in-data, ONE u64 atomic load per thread (768 pollers).
// ---------------------------------------------------------------------------

typedef __bf16 bf16x8 __attribute__((ext_vector_type(8)));
typedef float  f32x4  __attribute__((ext_vector_type(4)));
typedef unsigned long long u64;

__device__ __forceinline__ float bf2f(uint16_t v) {
    return __uint_as_float(((uint32_t)v) << 16);
}
__device__ __forceinline__ uint16_t f2bf(float f) {
    uint32_t u = __float_as_uint(f);
    uint32_t r = (u + 0x7fffu + ((u >> 16) & 1u)) >> 16;
    return (uint16_t)r;
}
__device__ __forceinline__ float sigf(float x) { return 1.0f / (1.0f + __expf(-x)); }
__device__ __forceinline__ float tanh_f(float x) {
    x = fminf(fmaxf(x, -15.0f), 15.0f);
    float e = __expf(2.0f * x);
    return (e - 1.0f) / (e + 1.0f);
}
__device__ __forceinline__ float dot8(uint4 w, const float* h, float acc) {
    acc = fmaf(__uint_as_float(w.x << 16),          h[0], acc);
    acc = fmaf(__uint_as_float(w.x & 0xffff0000u),  h[1], acc);
    acc = fmaf(__uint_as_float(w.y << 16),          h[2], acc);
    acc = fmaf(__uint_as_float(w.y & 0xffff0000u),  h[3], acc);
    acc = fmaf(__uint_as_float(w.z << 16),          h[4], acc);
    acc = fmaf(__uint_as_float(w.z & 0xffff0000u),  h[5], acc);
    acc = fmaf(__uint_as_float(w.w << 16),          h[6], acc);
    acc = fmaf(__uint_as_float(w.w & 0xffff0000u),  h[7], acc);
    return acc;
}

// ---------------------------------------------------------------------------
// K0a: dtype detector (fp32 read as bf16 halfwords shows exponent==0xFF).
// ---------------------------------------------------------------------------
__global__ __launch_bounds__(256)
void detect_mode(const uint16_t* __restrict__ p, int* __restrict__ mode)
{
    int i = blockIdx.x * 256 + threadIdx.x;
    uint16_t v = p[i];
    bool bad = ((v >> 7) & 0xFF) == 0xFF;
    if (__ballot(bad) != 0ull) {
        if ((threadIdx.x & 63) == 0) atomicOr(mode, 1);
    }
}

// ---------------------------------------------------------------------------
// K0b: canonicalize all tensors to bf16 (copy or downcast per mode).
// ---------------------------------------------------------------------------
struct ConvArgs {
    const void* src[14];
    void*       dst[14];
    int         n[14];
};

__global__ __launch_bounds__(256)
void conv_canon(ConvArgs a, const int* __restrict__ mode)
{
    int t = blockIdx.y;
    int n = a.n[t];
    int i = (blockIdx.x * 256 + threadIdx.x) * 8;
    if (i >= n) return;
    uint16_t* d = (uint16_t*)a.dst[t] + i;
    if (*mode) {
        const float* s = (const float*)a.src[t] + i;
        float4 v0 = reinterpret_cast<const float4*>(s)[0];
        float4 v1 = reinterpret_cast<const float4*>(s)[1];
        d[0] = f2bf(v0.x); d[1] = f2bf(v0.y); d[2] = f2bf(v0.z); d[3] = f2bf(v0.w);
        d[4] = f2bf(v1.x); d[5] = f2bf(v1.y); d[6] = f2bf(v1.z); d[7] = f2bf(v1.w);
    } else {
        *reinterpret_cast<uint4*>(d) =
            *reinterpret_cast<const uint4*>((const uint16_t*)a.src[t] + i);
    }
}

// ---------------------------------------------------------------------------
// K1: fused projection GEMM.  C(2048 x 6144) = A @ W^T + bias, K=768.
// seq region written PERMUTED for 16-wide wg ownership (48 wgs x 16 j):
//   idx = (j/16)*64 + g*16 + (j%16)
// ---------------------------------------------------------------------------
__global__ __launch_bounds__(256)
void gemm_pre(const uint16_t* __restrict__ treeF, const uint16_t* __restrict__ featF,
              const uint16_t* __restrict__ W_iou, const uint16_t* __restrict__ b_iou,
              const uint16_t* __restrict__ W_f,   const uint16_t* __restrict__ b_f,
              const uint16_t* __restrict__ W_ih,  const uint16_t* __restrict__ b_ih,
              const uint16_t* __restrict__ b_hh,
              uint16_t* __restrict__ x_iou, uint16_t* __restrict__ x_f,
              uint16_t* __restrict__ seq_pre)
{
    int lane = threadIdx.x & 63;
    int wave = threadIdx.x >> 6;
    int colTile = blockIdx.x * 4 + wave;     // 0..383
    int row0 = blockIdx.y * 16;              // 0..2032
    int cl = lane & 15, quad = lane >> 4;
    int colg = colTile * 16;

    const uint16_t* A; const uint16_t* W; int wrow;
    if (colTile < 144)      { A = treeF; W = W_iou; wrow = colg; }
    else if (colTile < 192) { A = treeF; W = W_f;   wrow = colg - 2304; }
    else                    { A = featF; W = W_ih;  wrow = colg - 3072; }

    const uint16_t* arow = A + (size_t)(row0 + cl) * 768 + quad * 8;
    const uint16_t* brow = W + (size_t)(wrow + cl) * 768 + quad * 8;

    f32x4 acc = {0.f, 0.f, 0.f, 0.f};
    for (int k = 0; k < 768; k += 32) {
        bf16x8 a = *reinterpret_cast<const bf16x8*>(arow + k);
        bf16x8 b = *reinterpret_cast<const bf16x8*>(brow + k);
        acc = __builtin_amdgcn_mfma_f32_16x16x32_bf16(a, b, acc, 0, 0, 0);
    }

    // C/D layout: col = lane&15, row = quad*4 + reg   [m89-verified]
    int outcol = colg + cl;
    float bias; uint16_t* dst; int ldc; int ccol;
    if (colTile < 144)      { bias = bf2f(b_iou[outcol]); dst = x_iou; ldc = 2304; ccol = outcol; }
    else if (colTile < 192) { int c = outcol - 2304; bias = bf2f(b_f[c]); dst = x_f; ldc = 768;  ccol = c; }
    else {
        int c = outcol - 3072;               // c = g*768 + j
        int g = c / 768, j = c - g * 768;
        bias = bf2f(b_ih[c]) + bf2f(b_hh[c]);
        dst = seq_pre; ldc = 3072;
        int wg = j >> 4, jr = j & 15;
        ccol = wg * 64 + g * 16 + jr;        // permuted for v7 ownership
    }
    for (int r = 0; r < 4; ++r) {
        int row = row0 + quad * 4 + r;
        dst[(size_t)row * ldc + ccol] = f2bf(acc[r] + bias);
    }
}

// ---------------------------------------------------------------------------
// K2a: per-level dot products (tree).
// ---------------------------------------------------------------------------
__global__ __launch_bounds__(256)
void tree_dots(int s, int m,
               const uint16_t* __restrict__ U_iou, const uint16_t* __restrict__ U_f,
               const uint16_t* __restrict__ x_f,
               uint16_t* __restrict__ x_iou, uint16_t* __restrict__ fdot,
               const float* __restrict__ tree_h)
{
    int id = blockIdx.x * 256 + threadIdx.x;
    int niou = m * 2304;
    if (id < niou) {
        int pl = id / 2304;
        int j = id - pl * 2304;
        int p = s + pl;
        int c1 = 2 * p + 1, c2 = 2 * p + 2;
        const uint16_t* urow = U_iou + (size_t)j * 768;
        const float* h1 = tree_h + (size_t)c1 * 768;
        float acc = 0.f;
        if (c2 < 2048) {
            const float* h2 = tree_h + (size_t)c2 * 768;
            for (int k = 0; k < 768; k += 8) {
                uint4 w = *reinterpret_cast<const uint4*>(urow + k);
                float hsum[8];
                #pragma unroll
                for (int i = 0; i < 8; ++i) hsum[i] = h1[k + i] + h2[k + i];
                acc = dot8(w, hsum, acc);
            }
        } else {
            for (int k = 0; k < 768; k += 8) {
                uint4 w = *reinterpret_cast<const uint4*>(urow + k);
                acc = dot8(w, h1 + k, acc);
            }
        }
        size_t off = (size_t)p * 2304 + j;
        x_iou[off] = f2bf(bf2f(x_iou[off]) + acc);
    } else {
        int e = id - niou;                 // < m*1536
        int eid = e / 768;
        int j = e - eid * 768;
        int p = s + (eid >> 1);
        int c = 2 * p + 1 + (eid & 1);
        if (c >= 2048) return;             // node 1023 has one child
        const uint16_t* urow = U_f + (size_t)j * 768;
        const float* hc = tree_h + (size_t)c * 768;
        float acc = 0.f;
        for (int k = 0; k < 768; k += 8) {
            uint4 w = *reinterpret_cast<const uint4*>(urow + k);
            acc = dot8(w, hc + k, acc);
        }
        fdot[(size_t)c * 768 + j] = f2bf(bf2f(x_f[(size_t)p * 768 + j]) + acc);
    }
}

// ---------------------------------------------------------------------------
// K2b: per-level combine (tree).
// ---------------------------------------------------------------------------
__global__ __launch_bounds__(256)
void tree_combine(int s, int m, const uint16_t* __restrict__ x_iou,
                  const uint16_t* __restrict__ fdot,
                  float* __restrict__ tree_h, float* __restrict__ tree_c)
{
    int id = blockIdx.x * 256 + threadIdx.x;
    int pl = id / 768;
    int j = id - pl * 768;
    int p = s + pl;
    const uint16_t* iou = x_iou + (size_t)p * 2304;
    float iv = sigf(bf2f(iou[j]));
    float ov = sigf(bf2f(iou[768 + j]));
    float uv = tanh_f(bf2f(iou[1536 + j]));
    float csum = 0.f;
    int c1 = 2 * p + 1, c2 = 2 * p + 2;
    if (c1 < 2048) csum += sigf(bf2f(fdot[(size_t)c1 * 768 + j])) * tree_c[(size_t)c1 * 768 + j];
    if (c2 < 2048) csum += sigf(bf2f(fdot[(size_t)c2 * 768 + j])) * tree_c[(size_t)c2 * 768 + j];
    float c = iv * uv + csum;
    tree_c[(size_t)p * 768 + j] = c;
    tree_h[(size_t)p * 768 + j] = ov * tanh_f(c);
}

// ---------------------------------------------------------------------------
// K3 v7: persistent sequential LSTM.  48 wgs x 1024 threads.
// Thread (jl=tid>>6 in 0..15, g=(tid>>4)&3, p=tid&15) holds W_hh row
// g*768 + (bid*16+jl), cols [p*48,p*48+48) PACKED bf16 in 6 uint4 (24 VGPR,
// v4-proven-resident idiom).  Each wave (64 lanes) = one owned j.
// h_comm: 2 parity buffers x 768 u64; word = (tag=t+1)<<32 | f32(h).
// Consume: threads 0..767 each spin on ONE u64 (single L3 round-trip),
// stage to parity LDS hl[t&1] (16 parts, stride 52: 8 bank-groups x 2-way,
// free per m136), ONE barrier, 48 dot8 MACs, shfl_xor reduce over 16 parts,
// shfl gather of 4 gates from lanes 0/16/32/48, replicated gate math,
// lane-0 publishes u64.  No trailing barrier (parity LDS: stage(t+1) writes
// the buffer compute(t) never reads; barrier(t+1) orders stage(t+2) after
// compute(t)).
// ---------------------------------------------------------------------------
#define SEQ_WGS 48
__global__ __launch_bounds__(1024)
void seq_lstm(const uint16_t* __restrict__ W_hh, const uint16_t* __restrict__ seq_pre,
              float* __restrict__ hs, u64* __restrict__ h_comm)
{
    __shared__ float hl[2][832];    // part p at hl[par][p*52 .. +48)

    int tid = threadIdx.x;
    int bid = blockIdx.x;           // 0..47
    int lane = tid & 63;
    int jl = tid >> 6;              // 0..15 (wave id = owned j)
    int g  = (tid >> 4) & 3;        // gate
    int p  = tid & 15;              // K-part
    int j  = bid * 16 + jl;         // owned h index (per wave)
    int row = g * 768 + j;          // W_hh row

    // weights into registers PACKED: cols [p*48, p*48+48) of row (24 VGPR)
    uint4 wq[6];
    {
        const uint16_t* src = W_hh + (size_t)row * 768 + p * 48;
        #pragma unroll
        for (int i = 0; i < 6; ++i)
            wq[i] = *reinterpret_cast<const uint4*>(src + i * 8);
    }

    // permuted seq_pre offset (wg reads contiguous 64 bf16 per step)
    int preOff = bid * 64 + g * 16 + jl;

    // poll/staging map: thread w=tid (<768) owns h word w
    int sp = tid / 48;
    int soff = tid - 48 * sp;
    int sdst = sp * 52 + soff;

    float cstate = 0.f;

    for (int t = 0; t < 2048; ++t) {
        float pre = bf2f(seq_pre[(size_t)t * 3072 + preOff]);  // prefetch
        float* hb = hl[t & 1];

        if (t > 0) {
            if (tid < 768) {
                const u64* hw = h_comm + (size_t)((t - 1) & 1) * 768 + tid;
                u64 a;
                int guard = 0;
                for (;;) {
                    a = __hip_atomic_load(hw, __ATOMIC_RELAXED,
                                          __HIP_MEMORY_SCOPE_AGENT);
                    if ((uint32_t)(a >> 32) >= (uint32_t)t) break;
                    if (++guard > (1 << 22)) break;      // hang bailout
                    __builtin_amdgcn_s_sleep(1);
                }
                hb[sdst] = __uint_as_float((uint32_t)a);
            }
        } else {
            if (tid < 768) hb[sdst] = 0.f;
        }
        __syncthreads();   // the ONLY barrier per step

        // 48 MACs over this thread's columns (packed bf16 weights, dot8)
        const float* hp = &hb[p * 52];
        float acc = 0.f;
        #pragma unroll
        for (int i = 0; i < 6; ++i)
            acc = dot8(wq[i], hp + i * 8, acc);

        // butterfly-reduce over p (lanes differing in bits 0..3)
        acc += __shfl_xor(acc, 1);
        acc += __shfl_xor(acc, 2);
        acc += __shfl_xor(acc, 4);
        acc += __shfl_xor(acc, 8);
        float gate = acc + pre;                  // uniform across 16-lane group

        // gather the 4 gates of this wave's j (p==0 lanes)
        float gi = __shfl(gate, 0);
        float gf = __shfl(gate, 16);
        float gg = __shfl(gate, 32);
        float go = __shfl(gate, 48);

        float iv = sigf(gi), fv = sigf(gf), gv = tanh_f(gg), ov = sigf(go);
        cstate = fv * cstate + iv * gv;          // replicated per wave
        float hv = ov * tanh_f(cstate);

        // publish: tag travels with data — single relaxed u64 store
        if (lane == 0) {
            u64 wd = ((u64)(uint32_t)(t + 1) << 32) | (u64)__float_as_uint(hv);
            __hip_atomic_store(h_comm + (size_t)(t & 1) * 768 + j, wd,
                               __ATOMIC_RELAXED, __HIP_MEMORY_SCOPE_AGENT);
            hs[(size_t)t * 768 + j] = hv;        // off critical path
        }
        // no trailing barrier (parity-buffered hl)
    }
}

// ---------------------------------------------------------------------------
// K4: classifier logits[n][o] = b_cls[o] + [tree_h[n] | hs[n]] . W_cls[o]
// ---------------------------------------------------------------------------
__global__ __launch_bounds__(128)
void cls_logits(const float* __restrict__ tree_h, const float* __restrict__ hs,
                const uint16_t* __restrict__ W_cls, const uint16_t* __restrict__ b_cls,
                float* __restrict__ logits)
{
    __shared__ float cin[1536];
    int n = blockIdx.x, tid = threadIdx.x;
    for (int k = tid; k < 768; k += 128) {
        cin[k]       = tree_h[(size_t)n * 768 + k];
        cin[768 + k] = hs[(size_t)n * 768 + k];
    }
    __syncthreads();
    const uint16_t* wrow = W_cls + (size_t)tid * 1536;
    float acc = bf2f(b_cls[tid]);
    for (int k = 0; k < 1536; k += 8) {
        uint4 w = *reinterpret_cast<const uint4*>(wrow + k);
        acc = dot8(w, cin + k, acc);
    }
    logits[(size_t)n * 128 + tid] = acc;
}

// ---------------------------------------------------------------------------
// K5: log_softmax over axis=0 per class column.  Output dtype per mode.
// ---------------------------------------------------------------------------
__global__ __launch_bounds__(256)
void col_softmax(const float* __restrict__ logits, void* __restrict__ out,
                 const int* __restrict__ mode)
{
    __shared__ float sred[256];
    int o = blockIdx.x, tid = threadIdx.x;
    float v[8];
    float mx = -1e30f;
    #pragma unroll
    for (int i = 0; i < 8; ++i) {
        v[i] = logits[(size_t)(i * 256 + tid) * 128 + o];
        mx = fmaxf(mx, v[i]);
    }
    sred[tid] = mx; __syncthreads();
    for (int s2 = 128; s2 > 0; s2 >>= 1) {
        if (tid < s2) sred[tid] = fmaxf(sred[tid], sred[tid + s2]);
        __syncthreads();
    }
    float M = sred[0]; __syncthreads();
    float sm = 0.f;
    #pragma unroll
    for (int i = 0; i < 8; ++i) sm += __expf(v[i] - M);
    sred[tid] = sm; __syncthreads();
    for (int s2 = 128; s2 > 0; s2 >>= 1) {
        if (tid < s2) sred[tid] += sred[tid + s2];
        __syncthreads();
    }
    float lse = M + logf(sred[0]);
    bool fp32 = (*mode != 0);
    #pragma unroll
    for (int i = 0; i < 8; ++i) {
        size_t idx = (size_t)(i * 256 + tid) * 128 + o;
        float val = v[i] - lse;
        if (fp32) ((float*)out)[idx] = val;
        else      ((uint16_t*)out)[idx] = f2bf(val);
    }
}

// ---------------------------------------------------------------------------
extern "C" void kernel_launch(void* const* d_in, const int* in_sizes, int n_in,
                              void* d_out, int out_size, void* d_ws, size_t ws_size,
                              hipStream_t stream)
{
    char* ws = (char*)d_ws;

    // ---- canonical bf16 tensor area (element offsets) ----
    static const int   CN[14] = {1572864, 1572864, 1769472, 1769472, 589824, 589824,
                                 2359296, 2359296, 196608, 2304, 768, 3072, 3072, 128};
    static const size_t COFF[14] = {0, 1572864, 3145728, 4915200, 6684672, 7274496,
                                    7864320, 10223616, 12582912, 12779520, 12781824,
                                    12782592, 12785664, 12788736};
    // canon slots: 0 treeF(d_in 0), 1 featF(1), 2 W_iou(2), 3 U_iou(4), 4 W_f(5),
    //              5 U_f(7), 6 W_ih(8), 7 W_hh(10), 8 W_cls(12), 9 b_iou(3),
    //              10 b_f(6), 11 b_ih(9), 12 b_hh(11), 13 b_cls(13)
    static const int SRCI[14] = {0, 1, 2, 4, 5, 7, 8, 10, 12, 3, 6, 9, 11, 13};

    uint16_t* canon = (uint16_t*)ws;
    const uint16_t* treeF = canon + COFF[0];
    const uint16_t* featF = canon + COFF[1];
    const uint16_t* W_iou = canon + COFF[2];
    const uint16_t* U_iou = canon + COFF[3];
    const uint16_t* W_f   = canon + COFF[4];
    const uint16_t* U_f   = canon + COFF[5];
    const uint16_t* W_ih  = canon + COFF[6];
    const uint16_t* W_hh  = canon + COFF[7];
    const uint16_t* W_cls = canon + COFF[8];
    const uint16_t* b_iou = canon + COFF[9];
    const uint16_t* b_f   = canon + COFF[10];
    const uint16_t* b_ih  = canon + COFF[11];
    const uint16_t* b_hh  = canon + COFF[12];
    const uint16_t* b_cls = canon + COFF[13];

    const size_t CANON_B = 25577728;                  // 12788864 el * 2
    uint16_t* x_iou   = (uint16_t*)(ws + CANON_B);            //  9437184 B
    uint16_t* seq_pre = (uint16_t*)(ws + CANON_B + 9437184);  // 12582912 B
    uint16_t* x_f     = (uint16_t*)(ws + CANON_B + 22020096); //  3145728 B
    uint16_t* fdot    = (uint16_t*)(ws + CANON_B + 25165824); //  3145728 B
    float*    tree_h  = (float*)   (ws + CANON_B + 28311552); //  6291456 B
    float*    tree_c  = (float*)   (ws + CANON_B + 34603008); //  6291456 B
    float*    hs      = (float*)   (ws + CANON_B + 40894464); //  6291456 B
    float*    logits  = (float*)   (ws + CANON_B + 47185920); //  1048576 B
    u64*      h_comm  = (u64*)     (ws + CANON_B + 48234496); //    12288 B (2x768 u64)
    int*      mode    = (int*)     (ws + CANON_B + 48246784); //      256 B
    const size_t WS_NEEDED = CANON_B + 48247040;              // ~70.4 MB
    if (ws_size < WS_NEEDED) return;  // diagnostic: out stays 0 (absmax ~8.56)

    hipMemsetAsync(h_comm, 0, 12288 + 256, stream);   // tags + mode

    detect_mode<<<256, 256, 0, stream>>>((const uint16_t*)d_in[0], mode);

    ConvArgs ca;
    for (int i = 0; i < 14; ++i) {
        ca.src[i] = d_in[SRCI[i]];
        ca.dst[i] = canon + COFF[i];
        ca.n[i]   = CN[i];
    }
    conv_canon<<<dim3(1152, 14), 256, 0, stream>>>(ca, mode);

    gemm_pre<<<dim3(96, 128), 256, 0, stream>>>(treeF, featF, W_iou, b_iou, W_f, b_f,
                                                W_ih, b_ih, b_hh, x_iou, x_f, seq_pre);

    // level 0 (leaves 1024..2047): combine only
    tree_combine<<<1024 * 3, 256, 0, stream>>>(1024, 1024, x_iou, fdot, tree_h, tree_c);
    for (int lvl = 1; lvl <= 11; ++lvl) {
        int s = (lvl == 11) ? 0 : (1 << (10 - lvl));
        int m = (lvl == 11) ? 1 : (1 << (10 - lvl));
        tree_dots<<<m * 15, 256, 0, stream>>>(s, m, U_iou, U_f, x_f, x_iou, fdot, tree_h);
        tree_combine<<<m * 3, 256, 0, stream>>>(s, m, x_iou, fdot, tree_h, tree_c);
    }

    seq_lstm<<<SEQ_WGS, 1024, 0, stream>>>(W_hh, seq_pre, hs, h_comm);

    cls_logits<<<2048, 128, 0, stream>>>(tree_h, hs, W_cls, b_cls, logits);
    col_softmax<<<128, 256, 0, stream>>>(logits, d_out, mode);
}

// Round 4
// 5305.030 us; speedup vs baseline: 1.5937x; 1.5937x over previous
//
#include <hip/hip_runtime.h>
#include <stdint.h>

// ---------------------------------------------------------------------------
// TreeLSTMParser: N=2048 nodes/timesteps, D_IN=H=768, OUT=128.
// Tree: complete binary tree, parent(i)=(i-1)/2; level L = [2^(10-L),2^(11-L))
// for L=1..10, level 0 = leaves [1024,2048), level 11 = {0}.
//
// Inputs fp32 (detector-confirmed r3).  All tensors canonicalized to bf16.
//
// seq_lstm v8: 24 wgs x 1024 threads, MFMA matvec core.
// r9 model (from the wg-count series 24->5540cyc, 32->6240, 48->8040,
// 128->7270): comm phase scales ~+100cyc/wg (poll-storm fabric contention;
// FETCH 58/147/176MB tracks wg count).  So pin comm at its optimum (v4's
// exact 24-wg protocol) and kill the compute phase with MFMA instead:
// X-operand = h broadcast to all 16 rows, Y-operand = 16 W_hh rows/tile.
// Per wg: 8 tiles x 2 K-halves = 16 waves x 12 mfma_16x16x32_bf16;
// weights 12 x bf16x8 = 48 VGPR (the only proven-resident idiom).
// Compute ~2000-3200cyc (192 VALU instr) -> ~300-400cyc.
// h published as bf16 payload in the tag u64 (tree path is already all-bf16).
// ---------------------------------------------------------------------------

typedef __bf16 bf16x8 __attribute__((ext_vector_type(8)));
typedef float  f32x4  __attribute__((ext_vector_type(4)));
typedef unsigned long long u64;

__device__ __forceinline__ float bf2f(uint16_t v) {
    return __uint_as_float(((uint32_t)v) << 16);
}
__device__ __forceinline__ uint16_t f2bf(float f) {
    uint32_t u = __float_as_uint(f);
    uint32_t r = (u + 0x7fffu + ((u >> 16) & 1u)) >> 16;
    return (uint16_t)r;
}
__device__ __forceinline__ float sigf(float x) { return 1.0f / (1.0f + __expf(-x)); }
__device__ __forceinline__ float tanh_f(float x) {
    x = fminf(fmaxf(x, -15.0f), 15.0f);
    float e = __expf(2.0f * x);
    return (e - 1.0f) / (e + 1.0f);
}
__device__ __forceinline__ float dot8(uint4 w, const float* h, float acc) {
    acc = fmaf(__uint_as_float(w.x << 16),          h[0], acc);
    acc = fmaf(__uint_as_float(w.x & 0xffff0000u),  h[1], acc);
    acc = fmaf(__uint_as_float(w.y << 16),          h[2], acc);
    acc = fmaf(__uint_as_float(w.y & 0xffff0000u),  h[3], acc);
    acc = fmaf(__uint_as_float(w.z << 16),          h[4], acc);
    acc = fmaf(__uint_as_float(w.z & 0xffff0000u),  h[5], acc);
    acc = fmaf(__uint_as_float(w.w << 16),          h[6], acc);
    acc = fmaf(__uint_as_float(w.w & 0xffff0000u),  h[7], acc);
    return acc;
}

// ---------------------------------------------------------------------------
// K0a: dtype detector (fp32 read as bf16 halfwords shows exponent==0xFF).
// ---------------------------------------------------------------------------
__global__ __launch_bounds__(256)
void detect_mode(const uint16_t* __restrict__ p, int* __restrict__ mode)
{
    int i = blockIdx.x * 256 + threadIdx.x;
    uint16_t v = p[i];
    bool bad = ((v >> 7) & 0xFF) == 0xFF;
    if (__ballot(bad) != 0ull) {
        if ((threadIdx.x & 63) == 0) atomicOr(mode, 1);
    }
}

// ---------------------------------------------------------------------------
// K0b: canonicalize all tensors to bf16 (copy or downcast per mode).
// ---------------------------------------------------------------------------
struct ConvArgs {
    const void* src[14];
    void*       dst[14];
    int         n[14];
};

__global__ __launch_bounds__(256)
void conv_canon(ConvArgs a, const int* __restrict__ mode)
{
    int t = blockIdx.y;
    int n = a.n[t];
    int i = (blockIdx.x * 256 + threadIdx.x) * 8;
    if (i >= n) return;
    uint16_t* d = (uint16_t*)a.dst[t] + i;
    if (*mode) {
        const float* s = (const float*)a.src[t] + i;
        float4 v0 = reinterpret_cast<const float4*>(s)[0];
        float4 v1 = reinterpret_cast<const float4*>(s)[1];
        d[0] = f2bf(v0.x); d[1] = f2bf(v0.y); d[2] = f2bf(v0.z); d[3] = f2bf(v0.w);
        d[4] = f2bf(v1.x); d[5] = f2bf(v1.y); d[6] = f2bf(v1.z); d[7] = f2bf(v1.w);
    } else {
        *reinterpret_cast<uint4*>(d) =
            *reinterpret_cast<const uint4*>((const uint16_t*)a.src[t] + i);
    }
}

// ---------------------------------------------------------------------------
// K1: fused projection GEMM.  C(2048 x 6144) = A @ W^T + bias, K=768.
// seq region written PERMUTED for 32-wide wg ownership (24 wgs x 32 j,
// v4 mapping): idx = (j>>5)*128 + g*32 + (j&31)
// ---------------------------------------------------------------------------
__global__ __launch_bounds__(256)
void gemm_pre(const uint16_t* __restrict__ treeF, const uint16_t* __restrict__ featF,
              const uint16_t* __restrict__ W_iou, const uint16_t* __restrict__ b_iou,
              const uint16_t* __restrict__ W_f,   const uint16_t* __restrict__ b_f,
              const uint16_t* __restrict__ W_ih,  const uint16_t* __restrict__ b_ih,
              const uint16_t* __restrict__ b_hh,
              uint16_t* __restrict__ x_iou, uint16_t* __restrict__ x_f,
              uint16_t* __restrict__ seq_pre)
{
    int lane = threadIdx.x & 63;
    int wave = threadIdx.x >> 6;
    int colTile = blockIdx.x * 4 + wave;     // 0..383
    int row0 = blockIdx.y * 16;              // 0..2032
    int cl = lane & 15, quad = lane >> 4;
    int colg = colTile * 16;

    const uint16_t* A; const uint16_t* W; int wrow;
    if (colTile < 144)      { A = treeF; W = W_iou; wrow = colg; }
    else if (colTile < 192) { A = treeF; W = W_f;   wrow = colg - 2304; }
    else                    { A = featF; W = W_ih;  wrow = colg - 3072; }

    const uint16_t* arow = A + (size_t)(row0 + cl) * 768 + quad * 8;
    const uint16_t* brow = W + (size_t)(wrow + cl) * 768 + quad * 8;

    f32x4 acc = {0.f, 0.f, 0.f, 0.f};
    for (int k = 0; k < 768; k += 32) {
        bf16x8 a = *reinterpret_cast<const bf16x8*>(arow + k);
        bf16x8 b = *reinterpret_cast<const bf16x8*>(brow + k);
        acc = __builtin_amdgcn_mfma_f32_16x16x32_bf16(a, b, acc, 0, 0, 0);
    }

    // C/D layout: col = lane&15, row = quad*4 + reg   [m89-verified]
    int outcol = colg + cl;
    float bias; uint16_t* dst; int ldc; int ccol;
    if (colTile < 144)      { bias = bf2f(b_iou[outcol]); dst = x_iou; ldc = 2304; ccol = outcol; }
    else if (colTile < 192) { int c = outcol - 2304; bias = bf2f(b_f[c]); dst = x_f; ldc = 768;  ccol = c; }
    else {
        int c = outcol - 3072;               // c = g*768 + j
        int g = c / 768, j = c - g * 768;
        bias = bf2f(b_ih[c]) + bf2f(b_hh[c]);
        dst = seq_pre; ldc = 3072;
        ccol = (j >> 5) * 128 + g * 32 + (j & 31);   // v4 permutation
    }
    for (int r = 0; r < 4; ++r) {
        int row = row0 + quad * 4 + r;
        dst[(size_t)row * ldc + ccol] = f2bf(acc[r] + bias);
    }
}

// ---------------------------------------------------------------------------
// K2a: per-level dot products (tree).
// ---------------------------------------------------------------------------
__global__ __launch_bounds__(256)
void tree_dots(int s, int m,
               const uint16_t* __restrict__ U_iou, const uint16_t* __restrict__ U_f,
               const uint16_t* __restrict__ x_f,
               uint16_t* __restrict__ x_iou, uint16_t* __restrict__ fdot,
               const float* __restrict__ tree_h)
{
    int id = blockIdx.x * 256 + threadIdx.x;
    int niou = m * 2304;
    if (id < niou) {
        int pl = id / 2304;
        int j = id - pl * 2304;
        int p = s + pl;
        int c1 = 2 * p + 1, c2 = 2 * p + 2;
        const uint16_t* urow = U_iou + (size_t)j * 768;
        const float* h1 = tree_h + (size_t)c1 * 768;
        float acc = 0.f;
        if (c2 < 2048) {
            const float* h2 = tree_h + (size_t)c2 * 768;
            for (int k = 0; k < 768; k += 8) {
                uint4 w = *reinterpret_cast<const uint4*>(urow + k);
                float hsum[8];
                #pragma unroll
                for (int i = 0; i < 8; ++i) hsum[i] = h1[k + i] + h2[k + i];
                acc = dot8(w, hsum, acc);
            }
        } else {
            for (int k = 0; k < 768; k += 8) {
                uint4 w = *reinterpret_cast<const uint4*>(urow + k);
                acc = dot8(w, h1 + k, acc);
            }
        }
        size_t off = (size_t)p * 2304 + j;
        x_iou[off] = f2bf(bf2f(x_iou[off]) + acc);
    } else {
        int e = id - niou;                 // < m*1536
        int eid = e / 768;
        int j = e - eid * 768;
        int p = s + (eid >> 1);
        int c = 2 * p + 1 + (eid & 1);
        if (c >= 2048) return;             // node 1023 has one child
        const uint16_t* urow = U_f + (size_t)j * 768;
        const float* hc = tree_h + (size_t)c * 768;
        float acc = 0.f;
        for (int k = 0; k < 768; k += 8) {
            uint4 w = *reinterpret_cast<const uint4*>(urow + k);
            acc = dot8(w, hc + k, acc);
        }
        fdot[(size_t)c * 768 + j] = f2bf(bf2f(x_f[(size_t)p * 768 + j]) + acc);
    }
}

// ---------------------------------------------------------------------------
// K2b: per-level combine (tree).
// ---------------------------------------------------------------------------
__global__ __launch_bounds__(256)
void tree_combine(int s, int m, const uint16_t* __restrict__ x_iou,
                  const uint16_t* __restrict__ fdot,
                  float* __restrict__ tree_h, float* __restrict__ tree_c)
{
    int id = blockIdx.x * 256 + threadIdx.x;
    int pl = id / 768;
    int j = id - pl * 768;
    int p = s + pl;
    const uint16_t* iou = x_iou + (size_t)p * 2304;
    float iv = sigf(bf2f(iou[j]));
    float ov = sigf(bf2f(iou[768 + j]));
    float uv = tanh_f(bf2f(iou[1536 + j]));
    float csum = 0.f;
    int c1 = 2 * p + 1, c2 = 2 * p + 2;
    if (c1 < 2048) csum += sigf(bf2f(fdot[(size_t)c1 * 768 + j])) * tree_c[(size_t)c1 * 768 + j];
    if (c2 < 2048) csum += sigf(bf2f(fdot[(size_t)c2 * 768 + j])) * tree_c[(size_t)c2 * 768 + j];
    float c = iv * uv + csum;
    tree_c[(size_t)p * 768 + j] = c;
    tree_h[(size_t)p * 768 + j] = ov * tanh_f(c);
}

// ---------------------------------------------------------------------------
// K3 v8: persistent sequential LSTM.  24 wgs x 1024 threads, MFMA core.
//
// Comm (byte-identical to v4's proven protocol, 24 wgs): h_comm = 2 parity
// buffers x 768 u64; word = (tag=t+1)<<32 | bf16(h) payload.  Threads 0..767
// each spin on ONE u64 (single L3 round-trip), stage payload to parity LDS
// hb16[t&1][tid], barrier.
//
// Compute: wave w (0..15): tile = w>>1 (16 W-rows of this wg's 128), khalf
// = w&1 (K 0..383 / 384..767).  Weights: 12 x bf16x8 = 48 VGPR.  MFMA with
// X = h broadcast into all 16 rows (lane l reads h[k-chunk l>>4], same addr
// for all 16 col-lanes = LDS broadcast), Y = W rows; result C[i][j=lane&15]
// identical over i -> acc[0] of lanes 0..15 = gate partials.  Partials to
// part[khalf][tile*16+lane], barrier, threads 0..31 (one per owned j) sum
// the 2 K-halves, add seq_pre, gate math, publish u64 + hs write.
//
// part[] single-buffered is safe: gate reads(t) < B1(t+1) < MFMA writes(t+1).
// hb16 parity: stage(t+2) writes hb16[t&1] only after B1(t+1) ordered past
// all MFMA reads(t).  Cross-wg parity reuse protected by the tag chain
// (publish(t+1) requires stage(t+1) which requires ALL wgs' publish(t)).
// ---------------------------------------------------------------------------
#define SEQ_WGS 24
__global__ __launch_bounds__(1024)
void seq_lstm(const uint16_t* __restrict__ W_hh, const uint16_t* __restrict__ seq_pre,
              float* __restrict__ hs, u64* __restrict__ h_comm)
{
    __shared__ uint16_t hb16[2][768];   // bf16 h, parity-buffered
    __shared__ float    part[2][128];   // [khalf][local row = g*32 + jl]

    int tid = threadIdx.x;
    int bid = blockIdx.x;           // 0..23
    int lane = tid & 63;
    int w    = tid >> 6;            // wave 0..15
    int tile = w >> 1;              // 0..7  (16 local W-rows each)
    int khalf = w & 1;              // K half: 0 -> [0,384), 1 -> [384,768)
    int tg = tile >> 1;                         // gate of this tile
    int tj = (tile & 1) * 16 + (lane & 15);     // jl of this lane's W row
    int rglob = tg * 768 + bid * 32 + tj;       // global W_hh row

    // weight fragments: lane l holds W[rglob][khalf*384 + ks*32 + (l>>4)*8 ..+8)
    bf16x8 wq[12];
    {
        const uint16_t* src = W_hh + (size_t)rglob * 768 + khalf * 384 + (lane >> 4) * 8;
        #pragma unroll
        for (int i = 0; i < 12; ++i)
            wq[i] = *reinterpret_cast<const bf16x8*>(src + i * 32);
    }

    float cstate = 0.f;             // live in threads 0..31 (jl = tid)

    for (int t = 0; t < 2048; ++t) {
        // gate-thread prefetch of seq_pre (4 gates, issued before the poll)
        float p0 = 0.f, p1 = 0.f, p2 = 0.f, p3 = 0.f;
        if (tid < 32) {
            const uint16_t* sp = seq_pre + (size_t)t * 3072 + bid * 128 + tid;
            p0 = bf2f(sp[0]);  p1 = bf2f(sp[32]);
            p2 = bf2f(sp[64]); p3 = bf2f(sp[96]);
        }

        uint16_t* hb = hb16[t & 1];
        if (t > 0) {
            if (tid < 768) {
                const u64* hw = h_comm + (size_t)((t - 1) & 1) * 768 + tid;
                u64 a;
                int guard = 0;
                for (;;) {
                    a = __hip_atomic_load(hw, __ATOMIC_RELAXED,
                                          __HIP_MEMORY_SCOPE_AGENT);
                    if ((uint32_t)(a >> 32) >= (uint32_t)t) break;
                    if (++guard > (1 << 22)) break;      // hang bailout
                    __builtin_amdgcn_s_sleep(1);
                }
                hb[tid] = (uint16_t)a;      // bf16 payload
            }
        } else {
            if (tid < 768) hb[tid] = 0;
        }
        __syncthreads();   // B1

        // matvec tile: 12 MFMA, X = h broadcast, Y = 16 W rows
        {
            const uint16_t* hbase = hb + khalf * 384 + (lane >> 4) * 8;
            f32x4 acc = {0.f, 0.f, 0.f, 0.f};
            #pragma unroll
            for (int ks = 0; ks < 12; ++ks) {
                bf16x8 hf = *reinterpret_cast<const bf16x8*>(hbase + ks * 32);
                acc = __builtin_amdgcn_mfma_f32_16x16x32_bf16(hf, wq[ks], acc, 0, 0, 0);
            }
            if ((lane >> 4) == 0)
                part[khalf][tile * 16 + lane] = acc[0];
        }
        __syncthreads();   // B2

        if (tid < 32) {
            int jl = tid;
            float gi = part[0][jl]      + part[1][jl]      + p0;
            float gf = part[0][32 + jl] + part[1][32 + jl] + p1;
            float gg = part[0][64 + jl] + part[1][64 + jl] + p2;
            float go = part[0][96 + jl] + part[1][96 + jl] + p3;

            float iv = sigf(gi), fv = sigf(gf), gv = tanh_f(gg), ov = sigf(go);
            cstate = fv * cstate + iv * gv;
            float hv = ov * tanh_f(cstate);

            int j = bid * 32 + jl;
            u64 wd = ((u64)(uint32_t)(t + 1) << 32) | (u64)(uint16_t)f2bf(hv);
            __hip_atomic_store(h_comm + (size_t)(t & 1) * 768 + j, wd,
                               __ATOMIC_RELAXED, __HIP_MEMORY_SCOPE_AGENT);
            hs[(size_t)t * 768 + j] = hv;        // off critical path
        }
        // no trailing barrier: hb16 parity + barrier chain protect reuse
    }
}

// ---------------------------------------------------------------------------
// K4: classifier logits[n][o] = b_cls[o] + [tree_h[n] | hs[n]] . W_cls[o]
// ---------------------------------------------------------------------------
__global__ __launch_bounds__(128)
void cls_logits(const float* __restrict__ tree_h, const float* __restrict__ hs,
                const uint16_t* __restrict__ W_cls, const uint16_t* __restrict__ b_cls,
                float* __restrict__ logits)
{
    __shared__ float cin[1536];
    int n = blockIdx.x, tid = threadIdx.x;
    for (int k = tid; k < 768; k += 128) {
        cin[k]       = tree_h[(size_t)n * 768 + k];
        cin[768 + k] = hs[(size_t)n * 768 + k];
    }
    __syncthreads();
    const uint16_t* wrow = W_cls + (size_t)tid * 1536;
    float acc = bf2f(b_cls[tid]);
    for (int k = 0; k < 1536; k += 8) {
        uint4 w = *reinterpret_cast<const uint4*>(wrow + k);
        acc = dot8(w, cin + k, acc);
    }
    logits[(size_t)n * 128 + tid] = acc;
}

// ---------------------------------------------------------------------------
// K5: log_softmax over axis=0 per class column.  Output dtype per mode.
// ---------------------------------------------------------------------------
__global__ __launch_bounds__(256)
void col_softmax(const float* __restrict__ logits, void* __restrict__ out,
                 const int* __restrict__ mode)
{
    __shared__ float sred[256];
    int o = blockIdx.x, tid = threadIdx.x;
    float v[8];
    float mx = -1e30f;
    #pragma unroll
    for (int i = 0; i < 8; ++i) {
        v[i] = logits[(size_t)(i * 256 + tid) * 128 + o];
        mx = fmaxf(mx, v[i]);
    }
    sred[tid] = mx; __syncthreads();
    for (int s2 = 128; s2 > 0; s2 >>= 1) {
        if (tid < s2) sred[tid] = fmaxf(sred[tid], sred[tid + s2]);
        __syncthreads();
    }
    float M = sred[0]; __syncthreads();
    float sm = 0.f;
    #pragma unroll
    for (int i = 0; i < 8; ++i) sm += __expf(v[i] - M);
    sred[tid] = sm; __syncthreads();
    for (int s2 = 128; s2 > 0; s2 >>= 1) {
        if (tid < s2) sred[tid] += sred[tid + s2];
        __syncthreads();
    }
    float lse = M + logf(sred[0]);
    bool fp32 = (*mode != 0);
    #pragma unroll
    for (int i = 0; i < 8; ++i) {
        size_t idx = (size_t)(i * 256 + tid) * 128 + o;
        float val = v[i] - lse;
        if (fp32) ((float*)out)[idx] = val;
        else      ((uint16_t*)out)[idx] = f2bf(val);
    }
}

// ---------------------------------------------------------------------------
extern "C" void kernel_launch(void* const* d_in, const int* in_sizes, int n_in,
                              void* d_out, int out_size, void* d_ws, size_t ws_size,
                              hipStream_t stream)
{
    char* ws = (char*)d_ws;

    // ---- canonical bf16 tensor area (element offsets) ----
    static const int   CN[14] = {1572864, 1572864, 1769472, 1769472, 589824, 589824,
                                 2359296, 2359296, 196608, 2304, 768, 3072, 3072, 128};
    static const size_t COFF[14] = {0, 1572864, 3145728, 4915200, 6684672, 7274496,
                                    7864320, 10223616, 12582912, 12779520, 12781824,
                                    12782592, 12785664, 12788736};
    // canon slots: 0 treeF(d_in 0), 1 featF(1), 2 W_iou(2), 3 U_iou(4), 4 W_f(5),
    //              5 U_f(7), 6 W_ih(8), 7 W_hh(10), 8 W_cls(12), 9 b_iou(3),
    //              10 b_f(6), 11 b_ih(9), 12 b_hh(11), 13 b_cls(13)
    static const int SRCI[14] = {0, 1, 2, 4, 5, 7, 8, 10, 12, 3, 6, 9, 11, 13};

    uint16_t* canon = (uint16_t*)ws;
    const uint16_t* treeF = canon + COFF[0];
    const uint16_t* featF = canon + COFF[1];
    const uint16_t* W_iou = canon + COFF[2];
    const uint16_t* U_iou = canon + COFF[3];
    const uint16_t* W_f   = canon + COFF[4];
    const uint16_t* U_f   = canon + COFF[5];
    const uint16_t* W_ih  = canon + COFF[6];
    const uint16_t* W_hh  = canon + COFF[7];
    const uint16_t* W_cls = canon + COFF[8];
    const uint16_t* b_iou = canon + COFF[9];
    const uint16_t* b_f   = canon + COFF[10];
    const uint16_t* b_ih  = canon + COFF[11];
    const uint16_t* b_hh  = canon + COFF[12];
    const uint16_t* b_cls = canon + COFF[13];

    const size_t CANON_B = 25577728;                  // 12788864 el * 2
    uint16_t* x_iou   = (uint16_t*)(ws + CANON_B);            //  9437184 B
    uint16_t* seq_pre = (uint16_t*)(ws + CANON_B + 9437184);  // 12582912 B
    uint16_t* x_f     = (uint16_t*)(ws + CANON_B + 22020096); //  3145728 B
    uint16_t* fdot    = (uint16_t*)(ws + CANON_B + 25165824); //  3145728 B
    float*    tree_h  = (float*)   (ws + CANON_B + 28311552); //  6291456 B
    float*    tree_c  = (float*)   (ws + CANON_B + 34603008); //  6291456 B
    float*    hs      = (float*)   (ws + CANON_B + 40894464); //  6291456 B
    float*    logits  = (float*)   (ws + CANON_B + 47185920); //  1048576 B
    u64*      h_comm  = (u64*)     (ws + CANON_B + 48234496); //    12288 B (2x768 u64)
    int*      mode    = (int*)     (ws + CANON_B + 48246784); //      256 B
    const size_t WS_NEEDED = CANON_B + 48247040;              // ~70.4 MB
    if (ws_size < WS_NEEDED) return;  // diagnostic: out stays 0 (absmax ~8.56)

    hipMemsetAsync(h_comm, 0, 12288 + 256, stream);   // tags + mode

    detect_mode<<<256, 256, 0, stream>>>((const uint16_t*)d_in[0], mode);

    ConvArgs ca;
    for (int i = 0; i < 14; ++i) {
        ca.src[i] = d_in[SRCI[i]];
        ca.dst[i] = canon + COFF[i];
        ca.n[i]   = CN[i];
    }
    conv_canon<<<dim3(1152, 14), 256, 0, stream>>>(ca, mode);

    gemm_pre<<<dim3(96, 128), 256, 0, stream>>>(treeF, featF, W_iou, b_iou, W_f, b_f,
                                                W_ih, b_ih, b_hh, x_iou, x_f, seq_pre);

    // level 0 (leaves 1024..2047): combine only
    tree_combine<<<1024 * 3, 256, 0, stream>>>(1024, 1024, x_iou, fdot, tree_h, tree_c);
    for (int lvl = 1; lvl <= 11; ++lvl) {
        int s = (lvl == 11) ? 0 : (1 << (10 - lvl));
        int m = (lvl == 11) ? 1 : (1 << (10 - lvl));
        tree_dots<<<m * 15, 256, 0, stream>>>(s, m, U_iou, U_f, x_f, x_iou, fdot, tree_h);
        tree_combine<<<m * 3, 256, 0, stream>>>(s, m, x_iou, fdot, tree_h, tree_c);
    }

    seq_lstm<<<SEQ_WGS, 1024, 0, stream>>>(W_hh, seq_pre, hs, h_comm);

    cls_logits<<<2048, 128, 0, stream>>>(tree_h, hs, W_cls, b_cls, logits);
    col_softmax<<<128, 256, 0, stream>>>(logits, d_out, mode);
}

// Round 5
// 5210.668 us; speedup vs baseline: 1.6226x; 1.0181x over previous
//
#include <hip/hip_runtime.h>
#include <stdint.h>

// ---------------------------------------------------------------------------
// TreeLSTMParser: N=2048 nodes/timesteps, D_IN=H=768, OUT=128.
// Tree: complete binary tree, parent(i)=(i-1)/2; level L = [2^(10-L),2^(11-L))
// for L=1..10, level 0 = leaves [1024,2048), level 11 = {0}.
//
// Inputs fp32 (detector-confirmed r3).  All tensors canonicalized to bf16.
//
// seq_lstm v9: v8 MFMA core + PACKED comm words (2 j per u64).
// r10 post-mortem of v8 (WIN, 4730->3310us): VALUBusy 6.3->1.37, MfmaUtil>0,
// FETCH back to 60MB => compute phase collapsed as predicted; step now
// ~3880cyc of which ~85% is comm (publish -> L3 -> 768-word poll detect).
// r10 theory: comm scales with poll traffic (wg series 24/32/48 wgs ->
// 5540/6240/8040cyc; FETCH tracks pollers).  v8 wasted 48 of each word's 64
// bits on tag.  v9 packs tag32 | bf16(h_odd) | bf16(h_even): polled words
// 768->384, lines 96->48, publisher stores 32->16 per wg.  Tail-of-max over
// half the transactions -> lower detect latency + less lockstep jitter.
// ---------------------------------------------------------------------------

typedef __bf16 bf16x8 __attribute__((ext_vector_type(8)));
typedef float  f32x4  __attribute__((ext_vector_type(4)));
typedef unsigned long long u64;

__device__ __forceinline__ float bf2f(uint16_t v) {
    return __uint_as_float(((uint32_t)v) << 16);
}
__device__ __forceinline__ uint16_t f2bf(float f) {
    uint32_t u = __float_as_uint(f);
    uint32_t r = (u + 0x7fffu + ((u >> 16) & 1u)) >> 16;
    return (uint16_t)r;
}
__device__ __forceinline__ float sigf(float x) { return 1.0f / (1.0f + __expf(-x)); }
__device__ __forceinline__ float tanh_f(float x) {
    x = fminf(fmaxf(x, -15.0f), 15.0f);
    float e = __expf(2.0f * x);
    return (e - 1.0f) / (e + 1.0f);
}
__device__ __forceinline__ float dot8(uint4 w, const float* h, float acc) {
    acc = fmaf(__uint_as_float(w.x << 16),          h[0], acc);
    acc = fmaf(__uint_as_float(w.x & 0xffff0000u),  h[1], acc);
    acc = fmaf(__uint_as_float(w.y << 16),          h[2], acc);
    acc = fmaf(__uint_as_float(w.y & 0xffff0000u),  h[3], acc);
    acc = fmaf(__uint_as_float(w.z << 16),          h[4], acc);
    acc = fmaf(__uint_as_float(w.z & 0xffff0000u),  h[5], acc);
    acc = fmaf(__uint_as_float(w.w << 16),          h[6], acc);
    acc = fmaf(__uint_as_float(w.w & 0xffff0000u),  h[7], acc);
    return acc;
}

// ---------------------------------------------------------------------------
// K0a: dtype detector (fp32 read as bf16 halfwords shows exponent==0xFF).
// ---------------------------------------------------------------------------
__global__ __launch_bounds__(256)
void detect_mode(const uint16_t* __restrict__ p, int* __restrict__ mode)
{
    int i = blockIdx.x * 256 + threadIdx.x;
    uint16_t v = p[i];
    bool bad = ((v >> 7) & 0xFF) == 0xFF;
    if (__ballot(bad) != 0ull) {
        if ((threadIdx.x & 63) == 0) atomicOr(mode, 1);
    }
}

// ---------------------------------------------------------------------------
// K0b: canonicalize all tensors to bf16 (copy or downcast per mode).
// ---------------------------------------------------------------------------
struct ConvArgs {
    const void* src[14];
    void*       dst[14];
    int         n[14];
};

__global__ __launch_bounds__(256)
void conv_canon(ConvArgs a, const int* __restrict__ mode)
{
    int t = blockIdx.y;
    int n = a.n[t];
    int i = (blockIdx.x * 256 + threadIdx.x) * 8;
    if (i >= n) return;
    uint16_t* d = (uint16_t*)a.dst[t] + i;
    if (*mode) {
        const float* s = (const float*)a.src[t] + i;
        float4 v0 = reinterpret_cast<const float4*>(s)[0];
        float4 v1 = reinterpret_cast<const float4*>(s)[1];
        d[0] = f2bf(v0.x); d[1] = f2bf(v0.y); d[2] = f2bf(v0.z); d[3] = f2bf(v0.w);
        d[4] = f2bf(v1.x); d[5] = f2bf(v1.y); d[6] = f2bf(v1.z); d[7] = f2bf(v1.w);
    } else {
        *reinterpret_cast<uint4*>(d) =
            *reinterpret_cast<const uint4*>((const uint16_t*)a.src[t] + i);
    }
}

// ---------------------------------------------------------------------------
// K1: fused projection GEMM.  C(2048 x 6144) = A @ W^T + bias, K=768.
// seq region written PERMUTED for 32-wide wg ownership (24 wgs x 32 j,
// v4 mapping): idx = (j>>5)*128 + g*32 + (j&31)
// ---------------------------------------------------------------------------
__global__ __launch_bounds__(256)
void gemm_pre(const uint16_t* __restrict__ treeF, const uint16_t* __restrict__ featF,
              const uint16_t* __restrict__ W_iou, const uint16_t* __restrict__ b_iou,
              const uint16_t* __restrict__ W_f,   const uint16_t* __restrict__ b_f,
              const uint16_t* __restrict__ W_ih,  const uint16_t* __restrict__ b_ih,
              const uint16_t* __restrict__ b_hh,
              uint16_t* __restrict__ x_iou, uint16_t* __restrict__ x_f,
              uint16_t* __restrict__ seq_pre)
{
    int lane = threadIdx.x & 63;
    int wave = threadIdx.x >> 6;
    int colTile = blockIdx.x * 4 + wave;     // 0..383
    int row0 = blockIdx.y * 16;              // 0..2032
    int cl = lane & 15, quad = lane >> 4;
    int colg = colTile * 16;

    const uint16_t* A; const uint16_t* W; int wrow;
    if (colTile < 144)      { A = treeF; W = W_iou; wrow = colg; }
    else if (colTile < 192) { A = treeF; W = W_f;   wrow = colg - 2304; }
    else                    { A = featF; W = W_ih;  wrow = colg - 3072; }

    const uint16_t* arow = A + (size_t)(row0 + cl) * 768 + quad * 8;
    const uint16_t* brow = W + (size_t)(wrow + cl) * 768 + quad * 8;

    f32x4 acc = {0.f, 0.f, 0.f, 0.f};
    for (int k = 0; k < 768; k += 32) {
        bf16x8 a = *reinterpret_cast<const bf16x8*>(arow + k);
        bf16x8 b = *reinterpret_cast<const bf16x8*>(brow + k);
        acc = __builtin_amdgcn_mfma_f32_16x16x32_bf16(a, b, acc, 0, 0, 0);
    }

    // C/D layout: col = lane&15, row = quad*4 + reg   [m89-verified]
    int outcol = colg + cl;
    float bias; uint16_t* dst; int ldc; int ccol;
    if (colTile < 144)      { bias = bf2f(b_iou[outcol]); dst = x_iou; ldc = 2304; ccol = outcol; }
    else if (colTile < 192) { int c = outcol - 2304; bias = bf2f(b_f[c]); dst = x_f; ldc = 768;  ccol = c; }
    else {
        int c = outcol - 3072;               // c = g*768 + j
        int g = c / 768, j = c - g * 768;
        bias = bf2f(b_ih[c]) + bf2f(b_hh[c]);
        dst = seq_pre; ldc = 3072;
        ccol = (j >> 5) * 128 + g * 32 + (j & 31);   // v4 permutation
    }
    for (int r = 0; r < 4; ++r) {
        int row = row0 + quad * 4 + r;
        dst[(size_t)row * ldc + ccol] = f2bf(acc[r] + bias);
    }
}

// ---------------------------------------------------------------------------
// K2a: per-level dot products (tree).
// ---------------------------------------------------------------------------
__global__ __launch_bounds__(256)
void tree_dots(int s, int m,
               const uint16_t* __restrict__ U_iou, const uint16_t* __restrict__ U_f,
               const uint16_t* __restrict__ x_f,
               uint16_t* __restrict__ x_iou, uint16_t* __restrict__ fdot,
               const float* __restrict__ tree_h)
{
    int id = blockIdx.x * 256 + threadIdx.x;
    int niou = m * 2304;
    if (id < niou) {
        int pl = id / 2304;
        int j = id - pl * 2304;
        int p = s + pl;
        int c1 = 2 * p + 1, c2 = 2 * p + 2;
        const uint16_t* urow = U_iou + (size_t)j * 768;
        const float* h1 = tree_h + (size_t)c1 * 768;
        float acc = 0.f;
        if (c2 < 2048) {
            const float* h2 = tree_h + (size_t)c2 * 768;
            for (int k = 0; k < 768; k += 8) {
                uint4 w = *reinterpret_cast<const uint4*>(urow + k);
                float hsum[8];
                #pragma unroll
                for (int i = 0; i < 8; ++i) hsum[i] = h1[k + i] + h2[k + i];
                acc = dot8(w, hsum, acc);
            }
        } else {
            for (int k = 0; k < 768; k += 8) {
                uint4 w = *reinterpret_cast<const uint4*>(urow + k);
                acc = dot8(w, h1 + k, acc);
            }
        }
        size_t off = (size_t)p * 2304 + j;
        x_iou[off] = f2bf(bf2f(x_iou[off]) + acc);
    } else {
        int e = id - niou;                 // < m*1536
        int eid = e / 768;
        int j = e - eid * 768;
        int p = s + (eid >> 1);
        int c = 2 * p + 1 + (eid & 1);
        if (c >= 2048) return;             // node 1023 has one child
        const uint16_t* urow = U_f + (size_t)j * 768;
        const float* hc = tree_h + (size_t)c * 768;
        float acc = 0.f;
        for (int k = 0; k < 768; k += 8) {
            uint4 w = *reinterpret_cast<const uint4*>(urow + k);
            acc = dot8(w, hc + k, acc);
        }
        fdot[(size_t)c * 768 + j] = f2bf(bf2f(x_f[(size_t)p * 768 + j]) + acc);
    }
}

// ---------------------------------------------------------------------------
// K2b: per-level combine (tree).
// ---------------------------------------------------------------------------
__global__ __launch_bounds__(256)
void tree_combine(int s, int m, const uint16_t* __restrict__ x_iou,
                  const uint16_t* __restrict__ fdot,
                  float* __restrict__ tree_h, float* __restrict__ tree_c)
{
    int id = blockIdx.x * 256 + threadIdx.x;
    int pl = id / 768;
    int j = id - pl * 768;
    int p = s + pl;
    const uint16_t* iou = x_iou + (size_t)p * 2304;
    float iv = sigf(bf2f(iou[j]));
    float ov = sigf(bf2f(iou[768 + j]));
    float uv = tanh_f(bf2f(iou[1536 + j]));
    float csum = 0.f;
    int c1 = 2 * p + 1, c2 = 2 * p + 2;
    if (c1 < 2048) csum += sigf(bf2f(fdot[(size_t)c1 * 768 + j])) * tree_c[(size_t)c1 * 768 + j];
    if (c2 < 2048) csum += sigf(bf2f(fdot[(size_t)c2 * 768 + j])) * tree_c[(size_t)c2 * 768 + j];
    float c = iv * uv + csum;
    tree_c[(size_t)p * 768 + j] = c;
    tree_h[(size_t)p * 768 + j] = ov * tanh_f(c);
}

// ---------------------------------------------------------------------------
// K3 v9: persistent sequential LSTM.  24 wgs x 1024 threads, MFMA core,
// packed comm (2 j per u64 word).
//
// h_comm: 2 parity buffers x 384 u64; word w covers j = {2w, 2w+1}:
//   wd = (tag=t+1)<<32 | bf16(h[2w+1])<<16 | bf16(h[2w]).
// Consume: threads 0..383 each spin on ONE u64, unpack 2 bf16 into parity
// LDS hb16[t&1], barrier B1.
// Compute (unchanged from v8): wave w: tile=w>>1 (16 W-rows), khalf=w&1.
// 12 MFMA with X = h broadcast, Y = 16 W rows; partials -> part[khalf][128],
// barrier B2; threads 0..31 sum halves + seq_pre, gate math; threads 0..15
// publish one packed u64 each (hv pair gathered via __shfl in wave 0).
//
// part[] single-buffered safe: gate reads(t) < B1(t+1) < MFMA writes(t+1).
// hb16 parity + tag chain protect cross-step reuse (v8-proven).
// ---------------------------------------------------------------------------
#define SEQ_WGS 24
__global__ __launch_bounds__(1024)
void seq_lstm(const uint16_t* __restrict__ W_hh, const uint16_t* __restrict__ seq_pre,
              float* __restrict__ hs, u64* __restrict__ h_comm)
{
    __shared__ uint16_t hb16[2][768];   // bf16 h, parity-buffered
    __shared__ float    part[2][128];   // [khalf][local row = g*32 + jl]

    int tid = threadIdx.x;
    int bid = blockIdx.x;           // 0..23
    int lane = tid & 63;
    int w    = tid >> 6;            // wave 0..15
    int tile = w >> 1;              // 0..7  (16 local W-rows each)
    int khalf = w & 1;              // K half: 0 -> [0,384), 1 -> [384,768)
    int tg = tile >> 1;                         // gate of this tile
    int tj = (tile & 1) * 16 + (lane & 15);     // jl of this lane's W row
    int rglob = tg * 768 + bid * 32 + tj;       // global W_hh row

    // weight fragments: lane l holds W[rglob][khalf*384 + ks*32 + (l>>4)*8 ..+8)
    bf16x8 wq[12];
    {
        const uint16_t* src = W_hh + (size_t)rglob * 768 + khalf * 384 + (lane >> 4) * 8;
        #pragma unroll
        for (int i = 0; i < 12; ++i)
            wq[i] = *reinterpret_cast<const bf16x8*>(src + i * 32);
    }

    float cstate = 0.f;             // live in threads 0..31 (jl = tid)

    for (int t = 0; t < 2048; ++t) {
        // gate-thread prefetch of seq_pre (4 gates, issued before the poll)
        float p0 = 0.f, p1 = 0.f, p2 = 0.f, p3 = 0.f;
        if (tid < 32) {
            const uint16_t* sp = seq_pre + (size_t)t * 3072 + bid * 128 + tid;
            p0 = bf2f(sp[0]);  p1 = bf2f(sp[32]);
            p2 = bf2f(sp[64]); p3 = bf2f(sp[96]);
        }

        uint16_t* hb = hb16[t & 1];
        if (t > 0) {
            if (tid < 384) {
                const u64* hw = h_comm + (size_t)((t - 1) & 1) * 384 + tid;
                u64 a;
                int guard = 0;
                for (;;) {
                    a = __hip_atomic_load(hw, __ATOMIC_RELAXED,
                                          __HIP_MEMORY_SCOPE_AGENT);
                    if ((uint32_t)(a >> 32) >= (uint32_t)t) break;
                    if (++guard > (1 << 22)) break;      // hang bailout
                    __builtin_amdgcn_s_sleep(1);
                }
                hb[2 * tid]     = (uint16_t)a;           // bf16 payload lo
                hb[2 * tid + 1] = (uint16_t)(a >> 16);   // bf16 payload hi
            }
        } else {
            if (tid < 768) hb[tid] = 0;
        }
        __syncthreads();   // B1

        // matvec tile: 12 MFMA, X = h broadcast, Y = 16 W rows
        {
            const uint16_t* hbase = hb + khalf * 384 + (lane >> 4) * 8;
            f32x4 acc = {0.f, 0.f, 0.f, 0.f};
            #pragma unroll
            for (int ks = 0; ks < 12; ++ks) {
                bf16x8 hf = *reinterpret_cast<const bf16x8*>(hbase + ks * 32);
                acc = __builtin_amdgcn_mfma_f32_16x16x32_bf16(hf, wq[ks], acc, 0, 0, 0);
            }
            if ((lane >> 4) == 0)
                part[khalf][tile * 16 + lane] = acc[0];
        }
        __syncthreads();   // B2

        if (tid < 32) {
            int jl = tid;
            float gi = part[0][jl]      + part[1][jl]      + p0;
            float gf = part[0][32 + jl] + part[1][32 + jl] + p1;
            float gg = part[0][64 + jl] + part[1][64 + jl] + p2;
            float go = part[0][96 + jl] + part[1][96 + jl] + p3;

            float iv = sigf(gi), fv = sigf(gf), gv = tanh_f(gg), ov = sigf(go);
            cstate = fv * cstate + iv * gv;
            float hv = ov * tanh_f(cstate);

            // pack 2 j per word; publisher = even jl's thread (q = jl>>1)
            uint32_t hb16v = (uint32_t)f2bf(hv);
            uint32_t hv_hi = __shfl(hb16v, 2 * (tid >> 1) + 1);  // odd partner
            uint32_t hv_lo = __shfl(hb16v, 2 * (tid >> 1));      // even partner
            if ((tid & 1) == 0) {
                int q = tid >> 1;                    // 0..15
                int wdx = bid * 16 + q;              // global word index
                u64 wd = ((u64)(uint32_t)(t + 1) << 32)
                       | ((u64)hv_hi << 16) | (u64)hv_lo;
                __hip_atomic_store(h_comm + (size_t)(t & 1) * 384 + wdx, wd,
                                   __ATOMIC_RELAXED, __HIP_MEMORY_SCOPE_AGENT);
            }
            int j = bid * 32 + jl;
            hs[(size_t)t * 768 + j] = hv;        // off critical path
        }
        // no trailing barrier: hb16 parity + barrier chain protect reuse
    }
}

// ---------------------------------------------------------------------------
// K4: classifier logits[n][o] = b_cls[o] + [tree_h[n] | hs[n]] . W_cls[o]
// ---------------------------------------------------------------------------
__global__ __launch_bounds__(128)
void cls_logits(const float* __restrict__ tree_h, const float* __restrict__ hs,
                const uint16_t* __restrict__ W_cls, const uint16_t* __restrict__ b_cls,
                float* __restrict__ logits)
{
    __shared__ float cin[1536];
    int n = blockIdx.x, tid = threadIdx.x;
    for (int k = tid; k < 768; k += 128) {
        cin[k]       = tree_h[(size_t)n * 768 + k];
        cin[768 + k] = hs[(size_t)n * 768 + k];
    }
    __syncthreads();
    const uint16_t* wrow = W_cls + (size_t)tid * 1536;
    float acc = bf2f(b_cls[tid]);
    for (int k = 0; k < 1536; k += 8) {
        uint4 w = *reinterpret_cast<const uint4*>(wrow + k);
        acc = dot8(w, cin + k, acc);
    }
    logits[(size_t)n * 128 + tid] = acc;
}

// ---------------------------------------------------------------------------
// K5: log_softmax over axis=0 per class column.  Output dtype per mode.
// ---------------------------------------------------------------------------
__global__ __launch_bounds__(256)
void col_softmax(const float* __restrict__ logits, void* __restrict__ out,
                 const int* __restrict__ mode)
{
    __shared__ float sred[256];
    int o = blockIdx.x, tid = threadIdx.x;
    float v[8];
    float mx = -1e30f;
    #pragma unroll
    for (int i = 0; i < 8; ++i) {
        v[i] = logits[(size_t)(i * 256 + tid) * 128 + o];
        mx = fmaxf(mx, v[i]);
    }
    sred[tid] = mx; __syncthreads();
    for (int s2 = 128; s2 > 0; s2 >>= 1) {
        if (tid < s2) sred[tid] = fmaxf(sred[tid], sred[tid + s2]);
        __syncthreads();
    }
    float M = sred[0]; __syncthreads();
    float sm = 0.f;
    #pragma unroll
    for (int i = 0; i < 8; ++i) sm += __expf(v[i] - M);
    sred[tid] = sm; __syncthreads();
    for (int s2 = 128; s2 > 0; s2 >>= 1) {
        if (tid < s2) sred[tid] += sred[tid + s2];
        __syncthreads();
    }
    float lse = M + logf(sred[0]);
    bool fp32 = (*mode != 0);
    #pragma unroll
    for (int i = 0; i < 8; ++i) {
        size_t idx = (size_t)(i * 256 + tid) * 128 + o;
        float val = v[i] - lse;
        if (fp32) ((float*)out)[idx] = val;
        else      ((uint16_t*)out)[idx] = f2bf(val);
    }
}

// ---------------------------------------------------------------------------
extern "C" void kernel_launch(void* const* d_in, const int* in_sizes, int n_in,
                              void* d_out, int out_size, void* d_ws, size_t ws_size,
                              hipStream_t stream)
{
    char* ws = (char*)d_ws;

    // ---- canonical bf16 tensor area (element offsets) ----
    static const int   CN[14] = {1572864, 1572864, 1769472, 1769472, 589824, 589824,
                                 2359296, 2359296, 196608, 2304, 768, 3072, 3072, 128};
    static const size_t COFF[14] = {0, 1572864, 3145728, 4915200, 6684672, 7274496,
                                    7864320, 10223616, 12582912, 12779520, 12781824,
                                    12782592, 12785664, 12788736};
    // canon slots: 0 treeF(d_in 0), 1 featF(1), 2 W_iou(2), 3 U_iou(4), 4 W_f(5),
    //              5 U_f(7), 6 W_ih(8), 7 W_hh(10), 8 W_cls(12), 9 b_iou(3),
    //              10 b_f(6), 11 b_ih(9), 12 b_hh(11), 13 b_cls(13)
    static const int SRCI[14] = {0, 1, 2, 4, 5, 7, 8, 10, 12, 3, 6, 9, 11, 13};

    uint16_t* canon = (uint16_t*)ws;
    const uint16_t* treeF = canon + COFF[0];
    const uint16_t* featF = canon + COFF[1];
    const uint16_t* W_iou = canon + COFF[2];
    const uint16_t* U_iou = canon + COFF[3];
    const uint16_t* W_f   = canon + COFF[4];
    const uint16_t* U_f   = canon + COFF[5];
    const uint16_t* W_ih  = canon + COFF[6];
    const uint16_t* W_hh  = canon + COFF[7];
    const uint16_t* W_cls = canon + COFF[8];
    const uint16_t* b_iou = canon + COFF[9];
    const uint16_t* b_f   = canon + COFF[10];
    const uint16_t* b_ih  = canon + COFF[11];
    const uint16_t* b_hh  = canon + COFF[12];
    const uint16_t* b_cls = canon + COFF[13];

    const size_t CANON_B = 25577728;                  // 12788864 el * 2
    uint16_t* x_iou   = (uint16_t*)(ws + CANON_B);            //  9437184 B
    uint16_t* seq_pre = (uint16_t*)(ws + CANON_B + 9437184);  // 12582912 B
    uint16_t* x_f     = (uint16_t*)(ws + CANON_B + 22020096); //  3145728 B
    uint16_t* fdot    = (uint16_t*)(ws + CANON_B + 25165824); //  3145728 B
    float*    tree_h  = (float*)   (ws + CANON_B + 28311552); //  6291456 B
    float*    tree_c  = (float*)   (ws + CANON_B + 34603008); //  6291456 B
    float*    hs      = (float*)   (ws + CANON_B + 40894464); //  6291456 B
    float*    logits  = (float*)   (ws + CANON_B + 47185920); //  1048576 B
    u64*      h_comm  = (u64*)     (ws + CANON_B + 48234496); //    12288 B (2x384 u64 used)
    int*      mode    = (int*)     (ws + CANON_B + 48246784); //      256 B
    const size_t WS_NEEDED = CANON_B + 48247040;              // ~70.4 MB
    if (ws_size < WS_NEEDED) return;  // diagnostic: out stays 0 (absmax ~8.56)

    hipMemsetAsync(h_comm, 0, 12288 + 256, stream);   // tags + mode

    detect_mode<<<256, 256, 0, stream>>>((const uint16_t*)d_in[0], mode);

    ConvArgs ca;
    for (int i = 0; i < 14; ++i) {
        ca.src[i] = d_in[SRCI[i]];
        ca.dst[i] = canon + COFF[i];
        ca.n[i]   = CN[i];
    }
    conv_canon<<<dim3(1152, 14), 256, 0, stream>>>(ca, mode);

    gemm_pre<<<dim3(96, 128), 256, 0, stream>>>(treeF, featF, W_iou, b_iou, W_f, b_f,
                                                W_ih, b_ih, b_hh, x_iou, x_f, seq_pre);

    // level 0 (leaves 1024..2047): combine only
    tree_combine<<<1024 * 3, 256, 0, stream>>>(1024, 1024, x_iou, fdot, tree_h, tree_c);
    for (int lvl = 1; lvl <= 11; ++lvl) {
        int s = (lvl == 11) ? 0 : (1 << (10 - lvl));
        int m = (lvl == 11) ? 1 : (1 << (10 - lvl));
        tree_dots<<<m * 15, 256, 0, stream>>>(s, m, U_iou, U_f, x_f, x_iou, fdot, tree_h);
        tree_combine<<<m * 3, 256, 0, stream>>>(s, m, x_iou, fdot, tree_h, tree_c);
    }

    seq_lstm<<<SEQ_WGS, 1024, 0, stream>>>(W_hh, seq_pre, hs, h_comm);

    cls_logits<<<2048, 128, 0, stream>>>(tree_h, hs, W_cls, b_cls, logits);
    col_softmax<<<128, 256, 0, stream>>>(logits, d_out, mode);
}

// Round 6
// 5171.550 us; speedup vs baseline: 1.6348x; 1.0076x over previous
//
#include <hip/hip_runtime.h>
#include <stdint.h>

// ---------------------------------------------------------------------------
// TreeLSTMParser: N=2048 nodes/timesteps, D_IN=H=768, OUT=128.
// Tree: complete binary tree, parent(i)=(i-1)/2; level L = [2^(10-L),2^(11-L))
// for L=1..10, level 0 = leaves [1024,2048), level 11 = {0}.
//
// Inputs fp32 (detector-confirmed r3).  All tensors canonicalized to bf16.
//
// seq_lstm v10: v9 (MFMA core + packed comm) + SINGLE-XCD PLACEMENT.
// r11 post-mortem of v9: FETCH halved (60->34MB) but dur -3% => comm is
// round-trip LATENCY-bound (pre-committed read).  The 24 wgs span 8 XCDs;
// publish->visibility crosses L3/fabric (~600-900cyc) serially in the tag
// chain.  v10 pins all 24 workers to ONE XCD via s_getreg(HW_REG_XCC_ID)
// [m09-verified] + ticket claim: h_comm lines then never leave that XCD's
// 4MB L2 -> poll round trip ~200-400cyc.  Launch 256 wgs; target XCD =
// first claimer's XCC (CAS); non-target wgs exit when ticket>=24, with
// timeout-fallback claim (degrades to v9 placement, never deadlocks).
// ---------------------------------------------------------------------------

typedef __bf16 bf16x8 __attribute__((ext_vector_type(8)));
typedef float  f32x4  __attribute__((ext_vector_type(4)));
typedef unsigned long long u64;

__device__ __forceinline__ float bf2f(uint16_t v) {
    return __uint_as_float(((uint32_t)v) << 16);
}
__device__ __forceinline__ uint16_t f2bf(float f) {
    uint32_t u = __float_as_uint(f);
    uint32_t r = (u + 0x7fffu + ((u >> 16) & 1u)) >> 16;
    return (uint16_t)r;
}
__device__ __forceinline__ float sigf(float x) { return 1.0f / (1.0f + __expf(-x)); }
__device__ __forceinline__ float tanh_f(float x) {
    x = fminf(fmaxf(x, -15.0f), 15.0f);
    float e = __expf(2.0f * x);
    return (e - 1.0f) / (e + 1.0f);
}
__device__ __forceinline__ float dot8(uint4 w, const float* h, float acc) {
    acc = fmaf(__uint_as_float(w.x << 16),          h[0], acc);
    acc = fmaf(__uint_as_float(w.x & 0xffff0000u),  h[1], acc);
    acc = fmaf(__uint_as_float(w.y << 16),          h[2], acc);
    acc = fmaf(__uint_as_float(w.y & 0xffff0000u),  h[3], acc);
    acc = fmaf(__uint_as_float(w.z << 16),          h[4], acc);
    acc = fmaf(__uint_as_float(w.z & 0xffff0000u),  h[5], acc);
    acc = fmaf(__uint_as_float(w.w << 16),          h[6], acc);
    acc = fmaf(__uint_as_float(w.w & 0xffff0000u),  h[7], acc);
    return acc;
}

// ---------------------------------------------------------------------------
// K0a: dtype detector (fp32 read as bf16 halfwords shows exponent==0xFF).
// ---------------------------------------------------------------------------
__global__ __launch_bounds__(256)
void detect_mode(const uint16_t* __restrict__ p, int* __restrict__ mode)
{
    int i = blockIdx.x * 256 + threadIdx.x;
    uint16_t v = p[i];
    bool bad = ((v >> 7) & 0xFF) == 0xFF;
    if (__ballot(bad) != 0ull) {
        if ((threadIdx.x & 63) == 0) atomicOr(mode, 1);
    }
}

// ---------------------------------------------------------------------------
// K0b: canonicalize all tensors to bf16 (copy or downcast per mode).
// ---------------------------------------------------------------------------
struct ConvArgs {
    const void* src[14];
    void*       dst[14];
    int         n[14];
};

__global__ __launch_bounds__(256)
void conv_canon(ConvArgs a, const int* __restrict__ mode)
{
    int t = blockIdx.y;
    int n = a.n[t];
    int i = (blockIdx.x * 256 + threadIdx.x) * 8;
    if (i >= n) return;
    uint16_t* d = (uint16_t*)a.dst[t] + i;
    if (*mode) {
        const float* s = (const float*)a.src[t] + i;
        float4 v0 = reinterpret_cast<const float4*>(s)[0];
        float4 v1 = reinterpret_cast<const float4*>(s)[1];
        d[0] = f2bf(v0.x); d[1] = f2bf(v0.y); d[2] = f2bf(v0.z); d[3] = f2bf(v0.w);
        d[4] = f2bf(v1.x); d[5] = f2bf(v1.y); d[6] = f2bf(v1.z); d[7] = f2bf(v1.w);
    } else {
        *reinterpret_cast<uint4*>(d) =
            *reinterpret_cast<const uint4*>((const uint16_t*)a.src[t] + i);
    }
}

// ---------------------------------------------------------------------------
// K1: fused projection GEMM.  C(2048 x 6144) = A @ W^T + bias, K=768.
// seq region written PERMUTED for 32-wide wg ownership (24 wgs x 32 j,
// v4 mapping): idx = (j>>5)*128 + g*32 + (j&31)
// ---------------------------------------------------------------------------
__global__ __launch_bounds__(256)
void gemm_pre(const uint16_t* __restrict__ treeF, const uint16_t* __restrict__ featF,
              const uint16_t* __restrict__ W_iou, const uint16_t* __restrict__ b_iou,
              const uint16_t* __restrict__ W_f,   const uint16_t* __restrict__ b_f,
              const uint16_t* __restrict__ W_ih,  const uint16_t* __restrict__ b_ih,
              const uint16_t* __restrict__ b_hh,
              uint16_t* __restrict__ x_iou, uint16_t* __restrict__ x_f,
              uint16_t* __restrict__ seq_pre)
{
    int lane = threadIdx.x & 63;
    int wave = threadIdx.x >> 6;
    int colTile = blockIdx.x * 4 + wave;     // 0..383
    int row0 = blockIdx.y * 16;              // 0..2032
    int cl = lane & 15, quad = lane >> 4;
    int colg = colTile * 16;

    const uint16_t* A; const uint16_t* W; int wrow;
    if (colTile < 144)      { A = treeF; W = W_iou; wrow = colg; }
    else if (colTile < 192) { A = treeF; W = W_f;   wrow = colg - 2304; }
    else                    { A = featF; W = W_ih;  wrow = colg - 3072; }

    const uint16_t* arow = A + (size_t)(row0 + cl) * 768 + quad * 8;
    const uint16_t* brow = W + (size_t)(wrow + cl) * 768 + quad * 8;

    f32x4 acc = {0.f, 0.f, 0.f, 0.f};
    for (int k = 0; k < 768; k += 32) {
        bf16x8 a = *reinterpret_cast<const bf16x8*>(arow + k);
        bf16x8 b = *reinterpret_cast<const bf16x8*>(brow + k);
        acc = __builtin_amdgcn_mfma_f32_16x16x32_bf16(a, b, acc, 0, 0, 0);
    }

    // C/D layout: col = lane&15, row = quad*4 + reg   [m89-verified]
    int outcol = colg + cl;
    float bias; uint16_t* dst; int ldc; int ccol;
    if (colTile < 144)      { bias = bf2f(b_iou[outcol]); dst = x_iou; ldc = 2304; ccol = outcol; }
    else if (colTile < 192) { int c = outcol - 2304; bias = bf2f(b_f[c]); dst = x_f; ldc = 768;  ccol = c; }
    else {
        int c = outcol - 3072;               // c = g*768 + j
        int g = c / 768, j = c - g * 768;
        bias = bf2f(b_ih[c]) + bf2f(b_hh[c]);
        dst = seq_pre; ldc = 3072;
        ccol = (j >> 5) * 128 + g * 32 + (j & 31);   // v4 permutation
    }
    for (int r = 0; r < 4; ++r) {
        int row = row0 + quad * 4 + r;
        dst[(size_t)row * ldc + ccol] = f2bf(acc[r] + bias);
    }
}

// ---------------------------------------------------------------------------
// K2a: per-level dot products (tree).
// ---------------------------------------------------------------------------
__global__ __launch_bounds__(256)
void tree_dots(int s, int m,
               const uint16_t* __restrict__ U_iou, const uint16_t* __restrict__ U_f,
               const uint16_t* __restrict__ x_f,
               uint16_t* __restrict__ x_iou, uint16_t* __restrict__ fdot,
               const float* __restrict__ tree_h)
{
    int id = blockIdx.x * 256 + threadIdx.x;
    int niou = m * 2304;
    if (id < niou) {
        int pl = id / 2304;
        int j = id - pl * 2304;
        int p = s + pl;
        int c1 = 2 * p + 1, c2 = 2 * p + 2;
        const uint16_t* urow = U_iou + (size_t)j * 768;
        const float* h1 = tree_h + (size_t)c1 * 768;
        float acc = 0.f;
        if (c2 < 2048) {
            const float* h2 = tree_h + (size_t)c2 * 768;
            for (int k = 0; k < 768; k += 8) {
                uint4 w = *reinterpret_cast<const uint4*>(urow + k);
                float hsum[8];
                #pragma unroll
                for (int i = 0; i < 8; ++i) hsum[i] = h1[k + i] + h2[k + i];
                acc = dot8(w, hsum, acc);
            }
        } else {
            for (int k = 0; k < 768; k += 8) {
                uint4 w = *reinterpret_cast<const uint4*>(urow + k);
                acc = dot8(w, h1 + k, acc);
            }
        }
        size_t off = (size_t)p * 2304 + j;
        x_iou[off] = f2bf(bf2f(x_iou[off]) + acc);
    } else {
        int e = id - niou;                 // < m*1536
        int eid = e / 768;
        int j = e - eid * 768;
        int p = s + (eid >> 1);
        int c = 2 * p + 1 + (eid & 1);
        if (c >= 2048) return;             // node 1023 has one child
        const uint16_t* urow = U_f + (size_t)j * 768;
        const float* hc = tree_h + (size_t)c * 768;
        float acc = 0.f;
        for (int k = 0; k < 768; k += 8) {
            uint4 w = *reinterpret_cast<const uint4*>(urow + k);
            acc = dot8(w, hc + k, acc);
        }
        fdot[(size_t)c * 768 + j] = f2bf(bf2f(x_f[(size_t)p * 768 + j]) + acc);
    }
}

// ---------------------------------------------------------------------------
// K2b: per-level combine (tree).
// ---------------------------------------------------------------------------
__global__ __launch_bounds__(256)
void tree_combine(int s, int m, const uint16_t* __restrict__ x_iou,
                  const uint16_t* __restrict__ fdot,
                  float* __restrict__ tree_h, float* __restrict__ tree_c)
{
    int id = blockIdx.x * 256 + threadIdx.x;
    int pl = id / 768;
    int j = id - pl * 768;
    int p = s + pl;
    const uint16_t* iou = x_iou + (size_t)p * 2304;
    float iv = sigf(bf2f(iou[j]));
    float ov = sigf(bf2f(iou[768 + j]));
    float uv = tanh_f(bf2f(iou[1536 + j]));
    float csum = 0.f;
    int c1 = 2 * p + 1, c2 = 2 * p + 2;
    if (c1 < 2048) csum += sigf(bf2f(fdot[(size_t)c1 * 768 + j])) * tree_c[(size_t)c1 * 768 + j];
    if (c2 < 2048) csum += sigf(bf2f(fdot[(size_t)c2 * 768 + j])) * tree_c[(size_t)c2 * 768 + j];
    float c = iv * uv + csum;
    tree_c[(size_t)p * 768 + j] = c;
    tree_h[(size_t)p * 768 + j] = ov * tanh_f(c);
}

// ---------------------------------------------------------------------------
// K3 v10: persistent sequential LSTM.  Launch 256 wgs x 1024 thr; exactly
// 24 WORKERS claim slots, preferentially all on ONE XCD (see header note).
// Worker body identical to v9: MFMA core + packed comm (2 j per u64).
//
// h_comm: 2 parity buffers x 384 u64; word w covers j = {2w, 2w+1}:
//   wd = (tag=t+1)<<32 | bf16(h[2w+1])<<16 | bf16(h[2w]).
// ctl[0] = ticket, ctl[1] = target XCC (init -1).
// ---------------------------------------------------------------------------
#define SEQ_WGS 24
#define SEQ_LAUNCH 256
__global__ __launch_bounds__(1024)
void seq_lstm(const uint16_t* __restrict__ W_hh, const uint16_t* __restrict__ seq_pre,
              float* __restrict__ hs, u64* __restrict__ h_comm, int* __restrict__ ctl)
{
    __shared__ uint16_t hb16[2][768];   // bf16 h, parity-buffered
    __shared__ float    part[2][128];   // [khalf][local row = g*32 + jl]
    __shared__ int      s_slot;

    int tid = threadIdx.x;

    // ---- placement claim: prefer one XCD for all workers ----
    int xcc;
    asm("s_getreg_b32 %0, hwreg(HW_REG_XCC_ID)" : "=s"(xcc));
    if (tid == 0) {
        int tgt = atomicCAS(&ctl[1], -1, xcc);   // first claimer sets target
        if (tgt == -1) tgt = xcc;
        int slot;
        if (xcc == tgt) {
            slot = atomicAdd(&ctl[0], 1);
        } else {
            int it = 0;
            for (;;) {
                int tk = __hip_atomic_load(&ctl[0], __ATOMIC_RELAXED,
                                           __HIP_MEMORY_SCOPE_AGENT);
                if (tk >= SEQ_WGS) { slot = 0x7fffffff; break; }  // filled: exit
                if (++it > 2000) { slot = atomicAdd(&ctl[0], 1); break; }  // fallback
                __builtin_amdgcn_s_sleep(8);
            }
        }
        s_slot = slot;
    }
    __syncthreads();
    int bid = s_slot;               // worker slot 0..23
    if (bid >= SEQ_WGS) return;     // non-worker wgs exit whole

    int lane = tid & 63;
    int w    = tid >> 6;            // wave 0..15
    int tile = w >> 1;              // 0..7  (16 local W-rows each)
    int khalf = w & 1;              // K half: 0 -> [0,384), 1 -> [384,768)
    int tg = tile >> 1;                         // gate of this tile
    int tj = (tile & 1) * 16 + (lane & 15);     // jl of this lane's W row
    int rglob = tg * 768 + bid * 32 + tj;       // global W_hh row

    // weight fragments: lane l holds W[rglob][khalf*384 + ks*32 + (l>>4)*8 ..+8)
    bf16x8 wq[12];
    {
        const uint16_t* src = W_hh + (size_t)rglob * 768 + khalf * 384 + (lane >> 4) * 8;
        #pragma unroll
        for (int i = 0; i < 12; ++i)
            wq[i] = *reinterpret_cast<const bf16x8*>(src + i * 32);
    }

    float cstate = 0.f;             // live in threads 0..31 (jl = tid)

    for (int t = 0; t < 2048; ++t) {
        // gate-thread prefetch of seq_pre (4 gates, issued before the poll)
        float p0 = 0.f, p1 = 0.f, p2 = 0.f, p3 = 0.f;
        if (tid < 32) {
            const uint16_t* sp = seq_pre + (size_t)t * 3072 + bid * 128 + tid;
            p0 = bf2f(sp[0]);  p1 = bf2f(sp[32]);
            p2 = bf2f(sp[64]); p3 = bf2f(sp[96]);
        }

        uint16_t* hb = hb16[t & 1];
        if (t > 0) {
            if (tid < 384) {
                const u64* hw = h_comm + (size_t)((t - 1) & 1) * 384 + tid;
                u64 a;
                int guard = 0;
                for (;;) {
                    a = __hip_atomic_load(hw, __ATOMIC_RELAXED,
                                          __HIP_MEMORY_SCOPE_AGENT);
                    if ((uint32_t)(a >> 32) >= (uint32_t)t) break;
                    if (++guard > (1 << 22)) break;      // hang bailout
                    __builtin_amdgcn_s_sleep(1);
                }
                hb[2 * tid]     = (uint16_t)a;           // bf16 payload lo
                hb[2 * tid + 1] = (uint16_t)(a >> 16);   // bf16 payload hi
            }
        } else {
            if (tid < 768) hb[tid] = 0;
        }
        __syncthreads();   // B1

        // matvec tile: 12 MFMA, X = h broadcast, Y = 16 W rows
        {
            const uint16_t* hbase = hb + khalf * 384 + (lane >> 4) * 8;
            f32x4 acc = {0.f, 0.f, 0.f, 0.f};
            #pragma unroll
            for (int ks = 0; ks < 12; ++ks) {
                bf16x8 hf = *reinterpret_cast<const bf16x8*>(hbase + ks * 32);
                acc = __builtin_amdgcn_mfma_f32_16x16x32_bf16(hf, wq[ks], acc, 0, 0, 0);
            }
            if ((lane >> 4) == 0)
                part[khalf][tile * 16 + lane] = acc[0];
        }
        __syncthreads();   // B2

        if (tid < 32) {
            int jl = tid;
            float gi = part[0][jl]      + part[1][jl]      + p0;
            float gf = part[0][32 + jl] + part[1][32 + jl] + p1;
            float gg = part[0][64 + jl] + part[1][64 + jl] + p2;
            float go = part[0][96 + jl] + part[1][96 + jl] + p3;

            float iv = sigf(gi), fv = sigf(gf), gv = tanh_f(gg), ov = sigf(go);
            cstate = fv * cstate + iv * gv;
            float hv = ov * tanh_f(cstate);

            // pack 2 j per word; publisher = even jl's thread (q = jl>>1)
            uint32_t hb16v = (uint32_t)f2bf(hv);
            uint32_t hv_hi = __shfl(hb16v, 2 * (tid >> 1) + 1);  // odd partner
            uint32_t hv_lo = __shfl(hb16v, 2 * (tid >> 1));      // even partner
            if ((tid & 1) == 0) {
                int q = tid >> 1;                    // 0..15
                int wdx = bid * 16 + q;              // global word index
                u64 wd = ((u64)(uint32_t)(t + 1) << 32)
                       | ((u64)hv_hi << 16) | (u64)hv_lo;
                __hip_atomic_store(h_comm + (size_t)(t & 1) * 384 + wdx, wd,
                                   __ATOMIC_RELAXED, __HIP_MEMORY_SCOPE_AGENT);
            }
            int j = bid * 32 + jl;
            hs[(size_t)t * 768 + j] = hv;        // off critical path
        }
        // no trailing barrier: hb16 parity + barrier chain protect reuse
    }
}

// ---------------------------------------------------------------------------
// K4: classifier logits[n][o] = b_cls[o] + [tree_h[n] | hs[n]] . W_cls[o]
// ---------------------------------------------------------------------------
__global__ __launch_bounds__(128)
void cls_logits(const float* __restrict__ tree_h, const float* __restrict__ hs,
                const uint16_t* __restrict__ W_cls, const uint16_t* __restrict__ b_cls,
                float* __restrict__ logits)
{
    __shared__ float cin[1536];
    int n = blockIdx.x, tid = threadIdx.x;
    for (int k = tid; k < 768; k += 128) {
        cin[k]       = tree_h[(size_t)n * 768 + k];
        cin[768 + k] = hs[(size_t)n * 768 + k];
    }
    __syncthreads();
    const uint16_t* wrow = W_cls + (size_t)tid * 1536;
    float acc = bf2f(b_cls[tid]);
    for (int k = 0; k < 1536; k += 8) {
        uint4 w = *reinterpret_cast<const uint4*>(wrow + k);
        acc = dot8(w, cin + k, acc);
    }
    logits[(size_t)n * 128 + tid] = acc;
}

// ---------------------------------------------------------------------------
// K5: log_softmax over axis=0 per class column.  Output dtype per mode.
// ---------------------------------------------------------------------------
__global__ __launch_bounds__(256)
void col_softmax(const float* __restrict__ logits, void* __restrict__ out,
                 const int* __restrict__ mode)
{
    __shared__ float sred[256];
    int o = blockIdx.x, tid = threadIdx.x;
    float v[8];
    float mx = -1e30f;
    #pragma unroll
    for (int i = 0; i < 8; ++i) {
        v[i] = logits[(size_t)(i * 256 + tid) * 128 + o];
        mx = fmaxf(mx, v[i]);
    }
    sred[tid] = mx; __syncthreads();
    for (int s2 = 128; s2 > 0; s2 >>= 1) {
        if (tid < s2) sred[tid] = fmaxf(sred[tid], sred[tid + s2]);
        __syncthreads();
    }
    float M = sred[0]; __syncthreads();
    float sm = 0.f;
    #pragma unroll
    for (int i = 0; i < 8; ++i) sm += __expf(v[i] - M);
    sred[tid] = sm; __syncthreads();
    for (int s2 = 128; s2 > 0; s2 >>= 1) {
        if (tid < s2) sred[tid] += sred[tid + s2];
        __syncthreads();
    }
    float lse = M + logf(sred[0]);
    bool fp32 = (*mode != 0);
    #pragma unroll
    for (int i = 0; i < 8; ++i) {
        size_t idx = (size_t)(i * 256 + tid) * 128 + o;
        float val = v[i] - lse;
        if (fp32) ((float*)out)[idx] = val;
        else      ((uint16_t*)out)[idx] = f2bf(val);
    }
}

// ---------------------------------------------------------------------------
extern "C" void kernel_launch(void* const* d_in, const int* in_sizes, int n_in,
                              void* d_out, int out_size, void* d_ws, size_t ws_size,
                              hipStream_t stream)
{
    char* ws = (char*)d_ws;

    // ---- canonical bf16 tensor area (element offsets) ----
    static const int   CN[14] = {1572864, 1572864, 1769472, 1769472, 589824, 589824,
                                 2359296, 2359296, 196608, 2304, 768, 3072, 3072, 128};
    static const size_t COFF[14] = {0, 1572864, 3145728, 4915200, 6684672, 7274496,
                                    7864320, 10223616, 12582912, 12779520, 12781824,
                                    12782592, 12785664, 12788736};
    // canon slots: 0 treeF(d_in 0), 1 featF(1), 2 W_iou(2), 3 U_iou(4), 4 W_f(5),
    //              5 U_f(7), 6 W_ih(8), 7 W_hh(10), 8 W_cls(12), 9 b_iou(3),
    //              10 b_f(6), 11 b_ih(9), 12 b_hh(11), 13 b_cls(13)
    static const int SRCI[14] = {0, 1, 2, 4, 5, 7, 8, 10, 12, 3, 6, 9, 11, 13};

    uint16_t* canon = (uint16_t*)ws;
    const uint16_t* treeF = canon + COFF[0];
    const uint16_t* featF = canon + COFF[1];
    const uint16_t* W_iou = canon + COFF[2];
    const uint16_t* U_iou = canon + COFF[3];
    const uint16_t* W_f   = canon + COFF[4];
    const uint16_t* U_f   = canon + COFF[5];
    const uint16_t* W_ih  = canon + COFF[6];
    const uint16_t* W_hh  = canon + COFF[7];
    const uint16_t* W_cls = canon + COFF[8];
    const uint16_t* b_iou = canon + COFF[9];
    const uint16_t* b_f   = canon + COFF[10];
    const uint16_t* b_ih  = canon + COFF[11];
    const uint16_t* b_hh  = canon + COFF[12];
    const uint16_t* b_cls = canon + COFF[13];

    const size_t CANON_B = 25577728;                  // 12788864 el * 2
    uint16_t* x_iou   = (uint16_t*)(ws + CANON_B);            //  9437184 B
    uint16_t* seq_pre = (uint16_t*)(ws + CANON_B + 9437184);  // 12582912 B
    uint16_t* x_f     = (uint16_t*)(ws + CANON_B + 22020096); //  3145728 B
    uint16_t* fdot    = (uint16_t*)(ws + CANON_B + 25165824); //  3145728 B
    float*    tree_h  = (float*)   (ws + CANON_B + 28311552); //  6291456 B
    float*    tree_c  = (float*)   (ws + CANON_B + 34603008); //  6291456 B
    float*    hs      = (float*)   (ws + CANON_B + 40894464); //  6291456 B
    float*    logits  = (float*)   (ws + CANON_B + 47185920); //  1048576 B
    u64*      h_comm  = (u64*)     (ws + CANON_B + 48234496); //    12288 B (2x384 u64 used)
    int*      mode    = (int*)     (ws + CANON_B + 48246784); //      256 B
    int*      ctl     = mode + 16;                            // ctl[0]=ticket, ctl[1]=target
    const size_t WS_NEEDED = CANON_B + 48247040;              // ~70.4 MB
    if (ws_size < WS_NEEDED) return;  // diagnostic: out stays 0 (absmax ~8.56)

    hipMemsetAsync(h_comm, 0, 12288 + 256, stream);   // tags + mode + ctl
    hipMemsetAsync(ctl + 1, 0xFF, 4, stream);         // target XCC = -1

    detect_mode<<<256, 256, 0, stream>>>((const uint16_t*)d_in[0], mode);

    ConvArgs ca;
    for (int i = 0; i < 14; ++i) {
        ca.src[i] = d_in[SRCI[i]];
        ca.dst[i] = canon + COFF[i];
        ca.n[i]   = CN[i];
    }
    conv_canon<<<dim3(1152, 14), 256, 0, stream>>>(ca, mode);

    gemm_pre<<<dim3(96, 128), 256, 0, stream>>>(treeF, featF, W_iou, b_iou, W_f, b_f,
                                                W_ih, b_ih, b_hh, x_iou, x_f, seq_pre);

    // level 0 (leaves 1024..2047): combine only
    tree_combine<<<1024 * 3, 256, 0, stream>>>(1024, 1024, x_iou, fdot, tree_h, tree_c);
    for (int lvl = 1; lvl <= 11; ++lvl) {
        int s = (lvl == 11) ? 0 : (1 << (10 - lvl));
        int m = (lvl == 11) ? 1 : (1 << (10 - lvl));
        tree_dots<<<m * 15, 256, 0, stream>>>(s, m, U_iou, U_f, x_f, x_iou, fdot, tree_h);
        tree_combine<<<m * 3, 256, 0, stream>>>(s, m, x_iou, fdot, tree_h, tree_c);
    }

    seq_lstm<<<SEQ_LAUNCH, 1024, 0, stream>>>(W_hh, seq_pre, hs, h_comm, ctl);

    cls_logits<<<2048, 128, 0, stream>>>(tree_h, hs, W_cls, b_cls, logits);
    col_softmax<<<128, 256, 0, stream>>>(logits, d_out, mode);
}

// Round 7
// 3573.557 us; speedup vs baseline: 2.3659x; 1.4472x over previous
//
#include <hip/hip_runtime.h>
#include <stdint.h>

// ---------------------------------------------------------------------------
// TreeLSTMParser: N=2048 nodes/timesteps, D_IN=H=768, OUT=128.
// Tree: complete binary tree, parent(i)=(i-1)/2; level L = [2^(10-L),2^(11-L))
// for L=1..10, level 0 = leaves [1024,2048), level 11 = {0}.
//
// Inputs fp32 (detector-confirmed r3).  All tensors canonicalized to bf16.
//
// v11: tail attack (pre-committed pivot after v10).
// seq_lstm v10 unchanged (MFMA core + packed comm + single-XCD claim,
// ~2950us; comm is structural agent-scope latency).  Tail was ~2.2ms:
//  - tree_dots: scalar dot8, U re-read per parent (~5.6GB L2) -> MFMA
//    16x16 tiles (gemm_pre fragment pattern), hsum via 2 chained MFMAs.
//    Needs bf16 h: tree_combine stores tree_hb (2049 rows; row 2048 = zeros
//    for node 1023's phantom child).
//  - cls_logits: scalar, W_cls re-read 805MB -> MFMA K=1536 over
//    [tree_hb | hs_b]; seq writes hs as bf16 (already bf16-rounded payload).
//  - tree_h fp32 dropped (no consumer left).
// ---------------------------------------------------------------------------

typedef __bf16 bf16x8 __attribute__((ext_vector_type(8)));
typedef float  f32x4  __attribute__((ext_vector_type(4)));
typedef unsigned long long u64;

__device__ __forceinline__ float bf2f(uint16_t v) {
    return __uint_as_float(((uint32_t)v) << 16);
}
__device__ __forceinline__ uint16_t f2bf(float f) {
    uint32_t u = __float_as_uint(f);
    uint32_t r = (u + 0x7fffu + ((u >> 16) & 1u)) >> 16;
    return (uint16_t)r;
}
__device__ __forceinline__ float sigf(float x) { return 1.0f / (1.0f + __expf(-x)); }
__device__ __forceinline__ float tanh_f(float x) {
    x = fminf(fmaxf(x, -15.0f), 15.0f);
    float e = __expf(2.0f * x);
    return (e - 1.0f) / (e + 1.0f);
}

// ---------------------------------------------------------------------------
// K0a: dtype detector (fp32 read as bf16 halfwords shows exponent==0xFF).
// ---------------------------------------------------------------------------
__global__ __launch_bounds__(256)
void detect_mode(const uint16_t* __restrict__ p, int* __restrict__ mode)
{
    int i = blockIdx.x * 256 + threadIdx.x;
    uint16_t v = p[i];
    bool bad = ((v >> 7) & 0xFF) == 0xFF;
    if (__ballot(bad) != 0ull) {
        if ((threadIdx.x & 63) == 0) atomicOr(mode, 1);
    }
}

// ---------------------------------------------------------------------------
// K0b: canonicalize all tensors to bf16 (copy or downcast per mode).
// ---------------------------------------------------------------------------
struct ConvArgs {
    const void* src[14];
    void*       dst[14];
    int         n[14];
};

__global__ __launch_bounds__(256)
void conv_canon(ConvArgs a, const int* __restrict__ mode)
{
    int t = blockIdx.y;
    int n = a.n[t];
    int i = (blockIdx.x * 256 + threadIdx.x) * 8;
    if (i >= n) return;
    uint16_t* d = (uint16_t*)a.dst[t] + i;
    if (*mode) {
        const float* s = (const float*)a.src[t] + i;
        float4 v0 = reinterpret_cast<const float4*>(s)[0];
        float4 v1 = reinterpret_cast<const float4*>(s)[1];
        d[0] = f2bf(v0.x); d[1] = f2bf(v0.y); d[2] = f2bf(v0.z); d[3] = f2bf(v0.w);
        d[4] = f2bf(v1.x); d[5] = f2bf(v1.y); d[6] = f2bf(v1.z); d[7] = f2bf(v1.w);
    } else {
        *reinterpret_cast<uint4*>(d) =
            *reinterpret_cast<const uint4*>((const uint16_t*)a.src[t] + i);
    }
}

// ---------------------------------------------------------------------------
// K1: fused projection GEMM.  C(2048 x 6144) = A @ W^T + bias, K=768.
// seq region written PERMUTED for 32-wide wg ownership (24 wgs x 32 j,
// v4 mapping): idx = (j>>5)*128 + g*32 + (j&31)
// ---------------------------------------------------------------------------
__global__ __launch_bounds__(256)
void gemm_pre(const uint16_t* __restrict__ treeF, const uint16_t* __restrict__ featF,
              const uint16_t* __restrict__ W_iou, const uint16_t* __restrict__ b_iou,
              const uint16_t* __restrict__ W_f,   const uint16_t* __restrict__ b_f,
              const uint16_t* __restrict__ W_ih,  const uint16_t* __restrict__ b_ih,
              const uint16_t* __restrict__ b_hh,
              uint16_t* __restrict__ x_iou, uint16_t* __restrict__ x_f,
              uint16_t* __restrict__ seq_pre)
{
    int lane = threadIdx.x & 63;
    int wave = threadIdx.x >> 6;
    int colTile = blockIdx.x * 4 + wave;     // 0..383
    int row0 = blockIdx.y * 16;              // 0..2032
    int cl = lane & 15, quad = lane >> 4;
    int colg = colTile * 16;

    const uint16_t* A; const uint16_t* W; int wrow;
    if (colTile < 144)      { A = treeF; W = W_iou; wrow = colg; }
    else if (colTile < 192) { A = treeF; W = W_f;   wrow = colg - 2304; }
    else                    { A = featF; W = W_ih;  wrow = colg - 3072; }

    const uint16_t* arow = A + (size_t)(row0 + cl) * 768 + quad * 8;
    const uint16_t* brow = W + (size_t)(wrow + cl) * 768 + quad * 8;

    f32x4 acc = {0.f, 0.f, 0.f, 0.f};
    for (int k = 0; k < 768; k += 32) {
        bf16x8 a = *reinterpret_cast<const bf16x8*>(arow + k);
        bf16x8 b = *reinterpret_cast<const bf16x8*>(brow + k);
        acc = __builtin_amdgcn_mfma_f32_16x16x32_bf16(a, b, acc, 0, 0, 0);
    }

    // C/D layout: col = lane&15, row = quad*4 + reg   [m89-verified]
    int outcol = colg + cl;
    float bias; uint16_t* dst; int ldc; int ccol;
    if (colTile < 144)      { bias = bf2f(b_iou[outcol]); dst = x_iou; ldc = 2304; ccol = outcol; }
    else if (colTile < 192) { int c = outcol - 2304; bias = bf2f(b_f[c]); dst = x_f; ldc = 768;  ccol = c; }
    else {
        int c = outcol - 3072;               // c = g*768 + j
        int g = c / 768, j = c - g * 768;
        bias = bf2f(b_ih[c]) + bf2f(b_hh[c]);
        dst = seq_pre; ldc = 3072;
        ccol = (j >> 5) * 128 + g * 32 + (j & 31);   // v4 permutation
    }
    for (int r = 0; r < 4; ++r) {
        int row = row0 + quad * 4 + r;
        dst[(size_t)row * ldc + ccol] = f2bf(acc[r] + bias);
    }
}

// ---------------------------------------------------------------------------
// K2a v2: per-level dot products (tree), MFMA.
// GEMM1: x_iou[p][j] += dot(U_iou[j], h[2p+1]+h[2p+2]), p-tile 16 x j-tile 16,
//        hsum via two chained MFMAs.  144 col tiles.
// GEMM2: fdot[c][j] = x_f[parent(c)][j] + dot(U_f[j], h[c]).  48 col tiles.
// hb row 2048 = zeros (node 1023 phantom child).  Row-clamp + store-guard
// handle partial tiles (m<16).
// ---------------------------------------------------------------------------
__global__ __launch_bounds__(256)
void tree_dots_mfma(int s, int m,
                    const uint16_t* __restrict__ U_iou, const uint16_t* __restrict__ U_f,
                    const uint16_t* __restrict__ x_f,
                    uint16_t* __restrict__ x_iou, uint16_t* __restrict__ fdot,
                    const uint16_t* __restrict__ hb)
{
    int lane = threadIdx.x & 63;
    int wave = threadIdx.x >> 6;
    int cl = lane & 15, quad = lane >> 4;
    int mt1 = (m + 15) >> 4;
    int mt2 = (2 * m + 15) >> 4;
    int t1 = mt1 * 144;
    int tile = blockIdx.x * 4 + wave;
    if (tile >= t1 + mt2 * 48) return;

    if (tile < t1) {
        int rt = tile / 144, ct = tile - rt * 144;
        int pl = rt * 16 + cl; if (pl > m - 1) pl = m - 1;   // A-row clamp
        int p = s + pl;
        const uint16_t* a1 = hb + (size_t)(2 * p + 1) * 768 + quad * 8;
        const uint16_t* a2 = hb + (size_t)(2 * p + 2) * 768 + quad * 8;
        const uint16_t* brow = U_iou + (size_t)(ct * 16 + cl) * 768 + quad * 8;
        f32x4 acc = {0.f, 0.f, 0.f, 0.f};
        for (int k = 0; k < 768; k += 32) {
            bf16x8 b = *reinterpret_cast<const bf16x8*>(brow + k);
            acc = __builtin_amdgcn_mfma_f32_16x16x32_bf16(
                      *reinterpret_cast<const bf16x8*>(a1 + k), b, acc, 0, 0, 0);
            acc = __builtin_amdgcn_mfma_f32_16x16x32_bf16(
                      *reinterpret_cast<const bf16x8*>(a2 + k), b, acc, 0, 0, 0);
        }
        int outcol = ct * 16 + cl;
        #pragma unroll
        for (int r = 0; r < 4; ++r) {
            int prow = rt * 16 + quad * 4 + r;
            if (prow < m) {
                size_t off = (size_t)(s + prow) * 2304 + outcol;
                x_iou[off] = f2bf(bf2f(x_iou[off]) + acc[r]);
            }
        }
    } else {
        int t2i = tile - t1;
        int rt = t2i / 48, ct = t2i - rt * 48;
        int c0 = 2 * s + 1;
        int rl = rt * 16 + cl; if (rl > 2 * m - 1) rl = 2 * m - 1;  // clamp
        const uint16_t* a = hb + (size_t)(c0 + rl) * 768 + quad * 8;
        const uint16_t* brow = U_f + (size_t)(ct * 16 + cl) * 768 + quad * 8;
        f32x4 acc = {0.f, 0.f, 0.f, 0.f};
        for (int k = 0; k < 768; k += 32) {
            acc = __builtin_amdgcn_mfma_f32_16x16x32_bf16(
                      *reinterpret_cast<const bf16x8*>(a + k),
                      *reinterpret_cast<const bf16x8*>(brow + k), acc, 0, 0, 0);
        }
        int outcol = ct * 16 + cl;
        #pragma unroll
        for (int r = 0; r < 4; ++r) {
            int rr = rt * 16 + quad * 4 + r;
            int c = c0 + rr;
            if (rr < 2 * m && c < 2048) {
                int p = (c - 1) >> 1;
                fdot[(size_t)c * 768 + outcol] =
                    f2bf(bf2f(x_f[(size_t)p * 768 + outcol]) + acc[r]);
            }
        }
    }
}

// ---------------------------------------------------------------------------
// K2b: per-level combine (tree).  Writes bf16 h (tree_hb) + fp32 c.
// ---------------------------------------------------------------------------
__global__ __launch_bounds__(256)
void tree_combine(int s, int m, const uint16_t* __restrict__ x_iou,
                  const uint16_t* __restrict__ fdot,
                  uint16_t* __restrict__ tree_hb, float* __restrict__ tree_c)
{
    int id = blockIdx.x * 256 + threadIdx.x;
    int pl = id / 768;
    int j = id - pl * 768;
    int p = s + pl;
    const uint16_t* iou = x_iou + (size_t)p * 2304;
    float iv = sigf(bf2f(iou[j]));
    float ov = sigf(bf2f(iou[768 + j]));
    float uv = tanh_f(bf2f(iou[1536 + j]));
    float csum = 0.f;
    int c1 = 2 * p + 1, c2 = 2 * p + 2;
    if (c1 < 2048) csum += sigf(bf2f(fdot[(size_t)c1 * 768 + j])) * tree_c[(size_t)c1 * 768 + j];
    if (c2 < 2048) csum += sigf(bf2f(fdot[(size_t)c2 * 768 + j])) * tree_c[(size_t)c2 * 768 + j];
    float c = iv * uv + csum;
    tree_c[(size_t)p * 768 + j] = c;
    tree_hb[(size_t)p * 768 + j] = f2bf(ov * tanh_f(c));
}

// ---------------------------------------------------------------------------
// K3 v10: persistent sequential LSTM.  Launch 256 wgs x 1024 thr; exactly
// 24 WORKERS claim slots, preferentially all on ONE XCD.  MFMA core +
// packed comm (2 j per u64).  hs written as bf16 (payload value).
// ---------------------------------------------------------------------------
#define SEQ_WGS 24
#define SEQ_LAUNCH 256
__global__ __launch_bounds__(1024)
void seq_lstm(const uint16_t* __restrict__ W_hh, const uint16_t* __restrict__ seq_pre,
              uint16_t* __restrict__ hsb, u64* __restrict__ h_comm, int* __restrict__ ctl)
{
    __shared__ uint16_t hb16[2][768];   // bf16 h, parity-buffered
    __shared__ float    part[2][128];   // [khalf][local row = g*32 + jl]
    __shared__ int      s_slot;

    int tid = threadIdx.x;

    // ---- placement claim: prefer one XCD for all workers ----
    int xcc;
    asm("s_getreg_b32 %0, hwreg(HW_REG_XCC_ID)" : "=s"(xcc));
    if (tid == 0) {
        int tgt = atomicCAS(&ctl[1], -1, xcc);   // first claimer sets target
        if (tgt == -1) tgt = xcc;
        int slot;
        if (xcc == tgt) {
            slot = atomicAdd(&ctl[0], 1);
        } else {
            int it = 0;
            for (;;) {
                int tk = __hip_atomic_load(&ctl[0], __ATOMIC_RELAXED,
                                           __HIP_MEMORY_SCOPE_AGENT);
                if (tk >= SEQ_WGS) { slot = 0x7fffffff; break; }  // filled: exit
                if (++it > 2000) { slot = atomicAdd(&ctl[0], 1); break; }  // fallback
                __builtin_amdgcn_s_sleep(8);
            }
        }
        s_slot = slot;
    }
    __syncthreads();
    int bid = s_slot;               // worker slot 0..23
    if (bid >= SEQ_WGS) return;     // non-worker wgs exit whole

    int lane = tid & 63;
    int w    = tid >> 6;            // wave 0..15
    int tile = w >> 1;              // 0..7  (16 local W-rows each)
    int khalf = w & 1;              // K half: 0 -> [0,384), 1 -> [384,768)
    int tg = tile >> 1;                         // gate of this tile
    int tj = (tile & 1) * 16 + (lane & 15);     // jl of this lane's W row
    int rglob = tg * 768 + bid * 32 + tj;       // global W_hh row

    // weight fragments: lane l holds W[rglob][khalf*384 + ks*32 + (l>>4)*8 ..+8)
    bf16x8 wq[12];
    {
        const uint16_t* src = W_hh + (size_t)rglob * 768 + khalf * 384 + (lane >> 4) * 8;
        #pragma unroll
        for (int i = 0; i < 12; ++i)
            wq[i] = *reinterpret_cast<const bf16x8*>(src + i * 32);
    }

    float cstate = 0.f;             // live in threads 0..31 (jl = tid)

    for (int t = 0; t < 2048; ++t) {
        // gate-thread prefetch of seq_pre (4 gates, issued before the poll)
        float p0 = 0.f, p1 = 0.f, p2 = 0.f, p3 = 0.f;
        if (tid < 32) {
            const uint16_t* sp = seq_pre + (size_t)t * 3072 + bid * 128 + tid;
            p0 = bf2f(sp[0]);  p1 = bf2f(sp[32]);
            p2 = bf2f(sp[64]); p3 = bf2f(sp[96]);
        }

        uint16_t* hb = hb16[t & 1];
        if (t > 0) {
            if (tid < 384) {
                const u64* hw = h_comm + (size_t)((t - 1) & 1) * 384 + tid;
                u64 a;
                int guard = 0;
                for (;;) {
                    a = __hip_atomic_load(hw, __ATOMIC_RELAXED,
                                          __HIP_MEMORY_SCOPE_AGENT);
                    if ((uint32_t)(a >> 32) >= (uint32_t)t) break;
                    if (++guard > (1 << 22)) break;      // hang bailout
                    __builtin_amdgcn_s_sleep(1);
                }
                hb[2 * tid]     = (uint16_t)a;           // bf16 payload lo
                hb[2 * tid + 1] = (uint16_t)(a >> 16);   // bf16 payload hi
            }
        } else {
            if (tid < 768) hb[tid] = 0;
        }
        __syncthreads();   // B1

        // matvec tile: 12 MFMA, X = h broadcast, Y = 16 W rows
        {
            const uint16_t* hbase = hb + khalf * 384 + (lane >> 4) * 8;
            f32x4 acc = {0.f, 0.f, 0.f, 0.f};
            #pragma unroll
            for (int ks = 0; ks < 12; ++ks) {
                bf16x8 hf = *reinterpret_cast<const bf16x8*>(hbase + ks * 32);
                acc = __builtin_amdgcn_mfma_f32_16x16x32_bf16(hf, wq[ks], acc, 0, 0, 0);
            }
            if ((lane >> 4) == 0)
                part[khalf][tile * 16 + lane] = acc[0];
        }
        __syncthreads();   // B2

        if (tid < 32) {
            int jl = tid;
            float gi = part[0][jl]      + part[1][jl]      + p0;
            float gf = part[0][32 + jl] + part[1][32 + jl] + p1;
            float gg = part[0][64 + jl] + part[1][64 + jl] + p2;
            float go = part[0][96 + jl] + part[1][96 + jl] + p3;

            float iv = sigf(gi), fv = sigf(gf), gv = tanh_f(gg), ov = sigf(go);
            cstate = fv * cstate + iv * gv;
            float hv = ov * tanh_f(cstate);

            // pack 2 j per word; publisher = even jl's thread (q = jl>>1)
            uint32_t hb16v = (uint32_t)f2bf(hv);
            uint32_t hv_hi = __shfl(hb16v, 2 * (tid >> 1) + 1);  // odd partner
            uint32_t hv_lo = __shfl(hb16v, 2 * (tid >> 1));      // even partner
            if ((tid & 1) == 0) {
                int q = tid >> 1;                    // 0..15
                int wdx = bid * 16 + q;              // global word index
                u64 wd = ((u64)(uint32_t)(t + 1) << 32)
                       | ((u64)hv_hi << 16) | (u64)hv_lo;
                __hip_atomic_store(h_comm + (size_t)(t & 1) * 384 + wdx, wd,
                                   __ATOMIC_RELAXED, __HIP_MEMORY_SCOPE_AGENT);
            }
            int j = bid * 32 + jl;
            hsb[(size_t)t * 768 + j] = (uint16_t)hb16v;   // off critical path
        }
        // no trailing barrier: hb16 parity + barrier chain protect reuse
    }
}

// ---------------------------------------------------------------------------
// K4 v2: classifier via MFMA.  logits[n][o] = b_cls[o] +
//   dot(W_cls[o][0:768], tree_hb[n]) + dot(W_cls[o][768:1536], hs_b[n]).
// 128 row tiles x 8 col tiles = 1024 tiles, 4 waves/block -> 256 blocks.
// ---------------------------------------------------------------------------
__global__ __launch_bounds__(256)
void cls_mfma(const uint16_t* __restrict__ hbT, const uint16_t* __restrict__ hsb,
              const uint16_t* __restrict__ W_cls, const uint16_t* __restrict__ b_cls,
              float* __restrict__ logits)
{
    int lane = threadIdx.x & 63;
    int wave = threadIdx.x >> 6;
    int cl = lane & 15, quad = lane >> 4;
    int tile = blockIdx.x * 4 + wave;    // 0..1023
    int rt = tile >> 3, ct = tile & 7;
    const uint16_t* a1 = hbT + (size_t)(rt * 16 + cl) * 768 + quad * 8;
    const uint16_t* a2 = hsb + (size_t)(rt * 16 + cl) * 768 + quad * 8;
    const uint16_t* brow = W_cls + (size_t)(ct * 16 + cl) * 1536 + quad * 8;
    f32x4 acc = {0.f, 0.f, 0.f, 0.f};
    for (int k = 0; k < 768; k += 32) {
        acc = __builtin_amdgcn_mfma_f32_16x16x32_bf16(
                  *reinterpret_cast<const bf16x8*>(a1 + k),
                  *reinterpret_cast<const bf16x8*>(brow + k), acc, 0, 0, 0);
        acc = __builtin_amdgcn_mfma_f32_16x16x32_bf16(
                  *reinterpret_cast<const bf16x8*>(a2 + k),
                  *reinterpret_cast<const bf16x8*>(brow + 768 + k), acc, 0, 0, 0);
    }
    int outcol = ct * 16 + cl;
    float bias = bf2f(b_cls[outcol]);
    #pragma unroll
    for (int r = 0; r < 4; ++r) {
        int n = rt * 16 + quad * 4 + r;
        logits[(size_t)n * 128 + outcol] = acc[r] + bias;
    }
}

// ---------------------------------------------------------------------------
// K5: log_softmax over axis=0 per class column.  Output dtype per mode.
// ---------------------------------------------------------------------------
__global__ __launch_bounds__(256)
void col_softmax(const float* __restrict__ logits, void* __restrict__ out,
                 const int* __restrict__ mode)
{
    __shared__ float sred[256];
    int o = blockIdx.x, tid = threadIdx.x;
    float v[8];
    float mx = -1e30f;
    #pragma unroll
    for (int i = 0; i < 8; ++i) {
        v[i] = logits[(size_t)(i * 256 + tid) * 128 + o];
        mx = fmaxf(mx, v[i]);
    }
    sred[tid] = mx; __syncthreads();
    for (int s2 = 128; s2 > 0; s2 >>= 1) {
        if (tid < s2) sred[tid] = fmaxf(sred[tid], sred[tid + s2]);
        __syncthreads();
    }
    float M = sred[0]; __syncthreads();
    float sm = 0.f;
    #pragma unroll
    for (int i = 0; i < 8; ++i) sm += __expf(v[i] - M);
    sred[tid] = sm; __syncthreads();
    for (int s2 = 128; s2 > 0; s2 >>= 1) {
        if (tid < s2) sred[tid] += sred[tid + s2];
        __syncthreads();
    }
    float lse = M + logf(sred[0]);
    bool fp32 = (*mode != 0);
    #pragma unroll
    for (int i = 0; i < 8; ++i) {
        size_t idx = (size_t)(i * 256 + tid) * 128 + o;
        float val = v[i] - lse;
        if (fp32) ((float*)out)[idx] = val;
        else      ((uint16_t*)out)[idx] = f2bf(val);
    }
}

// ---------------------------------------------------------------------------
extern "C" void kernel_launch(void* const* d_in, const int* in_sizes, int n_in,
                              void* d_out, int out_size, void* d_ws, size_t ws_size,
                              hipStream_t stream)
{
    char* ws = (char*)d_ws;

    // ---- canonical bf16 tensor area (element offsets) ----
    static const int   CN[14] = {1572864, 1572864, 1769472, 1769472, 589824, 589824,
                                 2359296, 2359296, 196608, 2304, 768, 3072, 3072, 128};
    static const size_t COFF[14] = {0, 1572864, 3145728, 4915200, 6684672, 7274496,
                                    7864320, 10223616, 12582912, 12779520, 12781824,
                                    12782592, 12785664, 12788736};
    // canon slots: 0 treeF(d_in 0), 1 featF(1), 2 W_iou(2), 3 U_iou(4), 4 W_f(5),
    //              5 U_f(7), 6 W_ih(8), 7 W_hh(10), 8 W_cls(12), 9 b_iou(3),
    //              10 b_f(6), 11 b_ih(9), 12 b_hh(11), 13 b_cls(13)
    static const int SRCI[14] = {0, 1, 2, 4, 5, 7, 8, 10, 12, 3, 6, 9, 11, 13};

    uint16_t* canon = (uint16_t*)ws;
    const uint16_t* treeF = canon + COFF[0];
    const uint16_t* featF = canon + COFF[1];
    const uint16_t* W_iou = canon + COFF[2];
    const uint16_t* U_iou = canon + COFF[3];
    const uint16_t* W_f   = canon + COFF[4];
    const uint16_t* U_f   = canon + COFF[5];
    const uint16_t* W_ih  = canon + COFF[6];
    const uint16_t* W_hh  = canon + COFF[7];
    const uint16_t* W_cls = canon + COFF[8];
    const uint16_t* b_iou = canon + COFF[9];
    const uint16_t* b_f   = canon + COFF[10];
    const uint16_t* b_ih  = canon + COFF[11];
    const uint16_t* b_hh  = canon + COFF[12];
    const uint16_t* b_cls = canon + COFF[13];

    const size_t CANON_B = 25577728;                  // 12788864 el * 2
    uint16_t* x_iou   = (uint16_t*)(ws + CANON_B);            //  9437184 B
    uint16_t* seq_pre = (uint16_t*)(ws + CANON_B + 9437184);  // 12582912 B
    uint16_t* x_f     = (uint16_t*)(ws + CANON_B + 22020096); //  3145728 B
    uint16_t* fdot    = (uint16_t*)(ws + CANON_B + 25165824); //  3145728 B
    uint16_t* tree_hb = (uint16_t*)(ws + CANON_B + 28311552); //  3147264 B (2049 rows)
    float*    tree_c  = (float*)   (ws + CANON_B + 31458816); //  6291456 B
    uint16_t* hs_b    = (uint16_t*)(ws + CANON_B + 37750272); //  3145728 B
    float*    logits  = (float*)   (ws + CANON_B + 40896000); //  1048576 B
    u64*      h_comm  = (u64*)     (ws + CANON_B + 41944576); //    12288 B (2x384 u64 used)
    int*      mode    = (int*)     (ws + CANON_B + 41956864); //      256 B
    int*      ctl     = mode + 16;                            // ctl[0]=ticket, ctl[1]=target
    const size_t WS_NEEDED = CANON_B + 41957120;              // ~64.4 MB
    if (ws_size < WS_NEEDED) return;  // diagnostic: out stays 0 (absmax ~8.56)

    hipMemsetAsync(h_comm, 0, 12288 + 256, stream);   // tags + mode + ctl
    hipMemsetAsync(ctl + 1, 0xFF, 4, stream);         // target XCC = -1
    hipMemsetAsync(tree_hb + (size_t)2048 * 768, 0, 1536, stream);  // phantom row

    detect_mode<<<256, 256, 0, stream>>>((const uint16_t*)d_in[0], mode);

    ConvArgs ca;
    for (int i = 0; i < 14; ++i) {
        ca.src[i] = d_in[SRCI[i]];
        ca.dst[i] = canon + COFF[i];
        ca.n[i]   = CN[i];
    }
    conv_canon<<<dim3(1152, 14), 256, 0, stream>>>(ca, mode);

    gemm_pre<<<dim3(96, 128), 256, 0, stream>>>(treeF, featF, W_iou, b_iou, W_f, b_f,
                                                W_ih, b_ih, b_hh, x_iou, x_f, seq_pre);

    // level 0 (leaves 1024..2047): combine only
    tree_combine<<<1024 * 3, 256, 0, stream>>>(1024, 1024, x_iou, fdot, tree_hb, tree_c);
    for (int lvl = 1; lvl <= 11; ++lvl) {
        int s = (lvl == 11) ? 0 : (1 << (10 - lvl));
        int m = (lvl == 11) ? 1 : (1 << (10 - lvl));
        int mt1 = (m + 15) >> 4, mt2 = (2 * m + 15) >> 4;
        int tiles = mt1 * 144 + mt2 * 48;
        tree_dots_mfma<<<(tiles + 3) / 4, 256, 0, stream>>>(s, m, U_iou, U_f, x_f,
                                                            x_iou, fdot, tree_hb);
        tree_combine<<<m * 3, 256, 0, stream>>>(s, m, x_iou, fdot, tree_hb, tree_c);
    }

    seq_lstm<<<SEQ_LAUNCH, 1024, 0, stream>>>(W_hh, seq_pre, hs_b, h_comm, ctl);

    cls_mfma<<<256, 256, 0, stream>>>(tree_hb, hs_b, W_cls, b_cls, logits);
    col_softmax<<<128, 256, 0, stream>>>(logits, d_out, mode);
}